// Round 2
// baseline (1490.094 us; speedup 1.0000x reference)
//
#include <hip/hip_runtime.h>
#include <cstdint>
#include <cstddef>

#define D_TOK 1024
#define NH 16
#define DH 64
#define BATCH 8
#define SEQ 4096
#define M_TOT (BATCH * SEQ)   // 32768

typedef unsigned short u16;
typedef __attribute__((ext_vector_type(8))) __bf16 bf16x8;
typedef __attribute__((ext_vector_type(4))) float f32x4;

constexpr float INV_SQRT_DH = 0.125f;  // 1/sqrt(64)

__device__ __forceinline__ u16 f32_to_bf16_rne(float f) {
  union { float f; uint32_t u; } c; c.f = f;
  uint32_t r = (c.u + 0x7FFFu + ((c.u >> 16) & 1u)) >> 16;
  return (u16)r;
}

// ---------------------------------------------------------------------------
// fp32 -> bf16 conversion (RNE), vectorized float4 -> ushort4.
// ---------------------------------------------------------------------------
__global__ __launch_bounds__(256) void cvt_f32_bf16(
    const float* __restrict__ in, u16* __restrict__ out, int n4) {
  int i = blockIdx.x * 256 + threadIdx.x;
  const int stride = gridDim.x * 256;
  for (; i < n4; i += stride) {
    const float4 v = reinterpret_cast<const float4*>(in)[i];
    ushort4 o;
    o.x = f32_to_bf16_rne(v.x);
    o.y = f32_to_bf16_rne(v.y);
    o.z = f32_to_bf16_rne(v.z);
    o.w = f32_to_bf16_rne(v.w);
    reinterpret_cast<ushort4*>(out)[i] = o;
  }
}

// ---------------------------------------------------------------------------
// bf16 MFMA GEMM (m97 structure): C[m,n] = sum_k A[m,k]*W[n,k] + bias[n]
// A: [M,1024] bf16 row-major; W: [1024,1024] bf16 row-major ([out,in]).
// MODE 0: C = acc+bias                    (fp32 out)
// MODE 1: C = (acc+bias)*aux[b*1024+n]    (fp32 out, per-batch col scale)
// MODE 2: C = (acc+bias)+aux[m*1024+n]    (fp32 out, residual)
// MODE 3: Cb = bf16((acc+bias)*aux[b*1024+n])  (bf16 out)
// BM=BN=128, BK=32, 256 thr (4 waves 2x2), wave tile 64x64 = 4x4 frags.
// LDS [kg][row][8] bf16: staging-linear AND conflict-free fragment reads.
// ---------------------------------------------------------------------------
template <int MODE>
__global__ __launch_bounds__(256) void gemm_bf16(
    const u16* __restrict__ A, const u16* __restrict__ W,
    const float* __restrict__ bias, float* __restrict__ C,
    u16* __restrict__ Cb, const float* __restrict__ aux) {
  __shared__ u16 Atile[4 * 128 * 8];  // 8 KiB: [kg][row][8]
  __shared__ u16 Btile[4 * 128 * 8];  // 8 KiB: [kg][col][8]

  const int tid = threadIdx.x;
  const int lane = tid & 63;
  const int wid = tid >> 6;       // 4 waves: 2x2
  const int wr = wid >> 1;        // wave row (0..1) -> 64-row half
  const int wc = wid & 1;         // wave col (0..1) -> 64-col half
  const int lr = lane & 15;       // fragment row/col
  const int kg = lane >> 4;       // k-group (0..3)

  const int bm0 = blockIdx.x * 128;
  const int bn0 = blockIdx.y * 128;
  const int b = bm0 >> 12;        // batch index (SEQ=4096)

  f32x4 acc[4][4];
#pragma unroll
  for (int i = 0; i < 4; i++)
#pragma unroll
    for (int j = 0; j < 4; j++) acc[i][j] = (f32x4)0.f;

  // staging chunk for this thread (per issue i): c = i*256 + tid
  // c -> (cg = c>>7, r = c&127); source row bm0+r (A) / bn0+r (B), k-chunk cg
  for (int k0 = 0; k0 < D_TOK; k0 += 32) {
    if (k0) __syncthreads();  // prev compute done before overwrite
#pragma unroll
    for (int i = 0; i < 2; i++) {
      const int c = i * 256 + tid;
      const int cg = c >> 7, r = c & 127;
      const u16* gpA = A + (size_t)(bm0 + r) * D_TOK + k0 + cg * 8;
      const u16* gpB = W + (size_t)(bn0 + r) * D_TOK + k0 + cg * 8;
      // wave-uniform LDS dest base; HW writes base + lane*16
      u16* ldA = &Atile[(size_t)(i * 256 + wid * 64) * 8];
      u16* ldB = &Btile[(size_t)(i * 256 + wid * 64) * 8];
      __builtin_amdgcn_global_load_lds(
          (const __attribute__((address_space(1))) void*)gpA,
          (__attribute__((address_space(3))) void*)ldA, 16, 0, 0);
      __builtin_amdgcn_global_load_lds(
          (const __attribute__((address_space(1))) void*)gpB,
          (__attribute__((address_space(3))) void*)ldB, 16, 0, 0);
    }
    __syncthreads();  // drains vmcnt(0): LDS tile ready

    bf16x8 af[4], bfr[4];
#pragma unroll
    for (int mi = 0; mi < 4; mi++)
      af[mi] = *reinterpret_cast<const bf16x8*>(
          &Atile[(size_t)(kg * 128 + wr * 64 + mi * 16 + lr) * 8]);
#pragma unroll
    for (int ni = 0; ni < 4; ni++)
      bfr[ni] = *reinterpret_cast<const bf16x8*>(
          &Btile[(size_t)(kg * 128 + wc * 64 + ni * 16 + lr) * 8]);
#pragma unroll
    for (int mi = 0; mi < 4; mi++)
#pragma unroll
      for (int ni = 0; ni < 4; ni++)
        acc[mi][ni] = __builtin_amdgcn_mfma_f32_16x16x32_bf16(
            af[mi], bfr[ni], acc[mi][ni], 0, 0, 0);
  }

  // Epilogue. D layout: col = lane&15, row = (lane>>4)*4 + reg  [m89/m91]
  float biasv[4], scv[4];
#pragma unroll
  for (int ni = 0; ni < 4; ni++) {
    const int n = bn0 + wc * 64 + ni * 16 + lr;
    biasv[ni] = bias[n];
    if (MODE == 1 || MODE == 3) scv[ni] = aux[(size_t)b * D_TOK + n];
  }
#pragma unroll
  for (int mi = 0; mi < 4; mi++) {
#pragma unroll
    for (int reg = 0; reg < 4; reg++) {
      const int m = bm0 + wr * 64 + mi * 16 + kg * 4 + reg;
#pragma unroll
      for (int ni = 0; ni < 4; ni++) {
        const int n = bn0 + wc * 64 + ni * 16 + lr;
        float o = acc[mi][ni][reg] + biasv[ni];
        if (MODE == 1 || MODE == 3) o *= scv[ni];
        if (MODE == 2) o += aux[(size_t)m * D_TOK + n];
        if (MODE == 3)
          Cb[(size_t)m * D_TOK + n] = f32_to_bf16_rne(o);
        else
          C[(size_t)m * D_TOK + n] = o;
      }
    }
  }
}

// ---------------------------------------------------------------------------
// alpha[t,h] = (dot(src[t,:], w[h,:]) + bias[h]) * inv_sqrt_dh
// One token per wave; W (16x1024 = 64KB) staged in LDS.
// ---------------------------------------------------------------------------
__global__ __launch_bounds__(256) void logits_kernel(
    const float* __restrict__ src, const float* __restrict__ w,
    const float* __restrict__ bias, float* __restrict__ alpha) {
  __shared__ float Wl[NH * D_TOK];  // 64 KB
  for (int i = threadIdx.x; i < NH * D_TOK; i += 256) Wl[i] = w[i];
  __syncthreads();

  const int lane = threadIdx.x & 63;
  const int wid = threadIdx.x >> 6;  // 4 waves per block
  for (int t = blockIdx.x * 4 + wid; t < M_TOT; t += gridDim.x * 4) {
    const float* row = src + (size_t)t * D_TOK;
    float acc[NH];
#pragma unroll
    for (int h = 0; h < NH; h++) acc[h] = 0.f;
    for (int i = 0; i < D_TOK / 64; i++) {
      const float x = row[lane + i * 64];
#pragma unroll
      for (int h = 0; h < NH; h++) acc[h] += x * Wl[h * D_TOK + lane + i * 64];
    }
#pragma unroll
    for (int h = 0; h < NH; h++) {
      float v = acc[h];
#pragma unroll
      for (int off = 32; off; off >>= 1) v += __shfl_xor(v, off, 64);
      acc[h] = v;
    }
    if (lane == 0) {
#pragma unroll
      for (int h = 0; h < NH; h++)
        alpha[(size_t)t * NH + h] = (acc[h] + bias[h]) * INV_SQRT_DH;
    }
  }
}

// ---------------------------------------------------------------------------
// Softmax over tokens per (b,h) + weighted pool:
//   g[b, h*64+dd] = sum_t softmax(alpha[b,:,h])[t] * src[b,t,h*64+dd]
// One block per (b,h). 512 threads = 8 waves.
// ---------------------------------------------------------------------------
__global__ __launch_bounds__(512) void pool_kernel(
    const float* __restrict__ alpha, const float* __restrict__ src,
    float* __restrict__ g) {
  __shared__ float wl[SEQ];  // 16 KB exp weights
  __shared__ float redbuf[8];
  __shared__ float pr[8][64];
  const int b = blockIdx.x >> 4;
  const int h = blockIdx.x & 15;
  const int tid = threadIdx.x;
  const int lane = tid & 63, wid = tid >> 6;

  // 1) load logits, block max
  float mx = -INFINITY;
  for (int t = tid; t < SEQ; t += 512) {
    const float a = alpha[((size_t)b * SEQ + t) * NH + h];
    wl[t] = a;
    mx = fmaxf(mx, a);
  }
#pragma unroll
  for (int off = 32; off; off >>= 1) mx = fmaxf(mx, __shfl_xor(mx, off, 64));
  if (lane == 0) redbuf[wid] = mx;
  __syncthreads();
  mx = redbuf[0];
#pragma unroll
  for (int i = 1; i < 8; i++) mx = fmaxf(mx, redbuf[i]);
  __syncthreads();  // all reads of redbuf done before reuse

  // 2) exp + block sum
  float s = 0.f;
  for (int t = tid; t < SEQ; t += 512) {
    const float e = __expf(wl[t] - mx);
    wl[t] = e;
    s += e;
  }
#pragma unroll
  for (int off = 32; off; off >>= 1) s += __shfl_xor(s, off, 64);
  if (lane == 0) redbuf[wid] = s;
  __syncthreads();
  float tot = 0.f;
#pragma unroll
  for (int i = 0; i < 8; i++) tot += redbuf[i];
  const float inv = 1.0f / tot;

  // 3) weighted pool over tokens
  const int dd = tid & 63;
  const int ch = tid >> 6;
  const float* sp = src + (size_t)b * SEQ * D_TOK + h * DH + dd;
  float acc = 0.f;
  for (int t = ch; t < SEQ; t += 8) acc += wl[t] * sp[(size_t)t * D_TOK];
  pr[ch][dd] = acc;
  __syncthreads();
  if (tid < 64) {
    float s2 = 0.f;
#pragma unroll
    for (int c = 0; c < 8; c++) s2 += pr[c][tid];
    g[(size_t)b * D_TOK + h * DH + tid] = s2 * inv;
  }
}

// ---------------------------------------------------------------------------
extern "C" void kernel_launch(void* const* d_in, const int* in_sizes, int n_in,
                              void* d_out, int out_size, void* d_ws,
                              size_t ws_size, hipStream_t stream) {
  const float* x_q   = (const float*)d_in[0];
  const float* x_kv  = (const float*)d_in[1];
  const float* q_w   = (const float*)d_in[2];
  const float* k_w   = (const float*)d_in[3];
  const float* v_w   = (const float*)d_in[4];
  const float* wq_w  = (const float*)d_in[5];
  const float* wk_w  = (const float*)d_in[6];
  const float* out_w = (const float*)d_in[7];
  const float* q_b   = (const float*)d_in[8];
  const float* k_b   = (const float*)d_in[9];
  const float* v_b   = (const float*)d_in[10];
  const float* wq_b  = (const float*)d_in[11];
  const float* wk_b  = (const float*)d_in[12];
  const float* out_b = (const float*)d_in[13];
  float* out = (float*)d_out;

  char* ws = (char*)d_ws;
  const size_t SZ_F32 = (size_t)M_TOT * D_TOK * sizeof(float);  // 128 MiB
  const size_t SZ_BF  = (size_t)M_TOT * D_TOK * sizeof(u16);    // 64 MiB
  const size_t SZ_WBF = (size_t)D_TOK * D_TOK * sizeof(u16);    // 2 MiB
  size_t off = 0;
  float* q      = (float*)(ws + off); off += SZ_F32;
  float* p      = (float*)(ws + off); off += SZ_F32;
  u16*   xq_bf  = (u16*)(ws + off);   off += SZ_BF;   // reused as u_bf
  u16*   xkv_bf = (u16*)(ws + off);   off += SZ_BF;
  u16*   qw_bf  = (u16*)(ws + off);   off += SZ_WBF;
  u16*   kw_bf  = (u16*)(ws + off);   off += SZ_WBF;
  u16*   vw_bf  = (u16*)(ws + off);   off += SZ_WBF;
  u16*   ow_bf  = (u16*)(ws + off);   off += SZ_WBF;
  float* al     = (float*)(ws + off); off += (size_t)M_TOT * NH * sizeof(float);
  float* qg     = (float*)(ws + off); off += (size_t)BATCH * D_TOK * sizeof(float);
  float* kglob  = (float*)(ws + off); off += (size_t)BATCH * D_TOK * sizeof(float);
  u16* u_bf = xq_bf;  // x_q_bf dead after GEMM1; u written by GEMM3

  const int NX4 = M_TOT * D_TOK / 4;   // 8M float4 per activation
  const int NW4 = D_TOK * D_TOK / 4;   // 256K float4 per weight

  // fp32 -> bf16 conversions
  cvt_f32_bf16<<<2048, 256, 0, stream>>>(x_q,   xq_bf,  NX4);
  cvt_f32_bf16<<<2048, 256, 0, stream>>>(x_kv,  xkv_bf, NX4);
  cvt_f32_bf16<<<512,  256, 0, stream>>>(q_w,   qw_bf,  NW4);
  cvt_f32_bf16<<<512,  256, 0, stream>>>(k_w,   kw_bf,  NW4);
  cvt_f32_bf16<<<512,  256, 0, stream>>>(v_w,   vw_bf,  NW4);
  cvt_f32_bf16<<<512,  256, 0, stream>>>(out_w, ow_bf,  NW4);

  const dim3 gg(M_TOT / 128, D_TOK / 128), gb(256);

  // q = x_q @ q_w^T + q_b
  gemm_bf16<0><<<gg, gb, 0, stream>>>(xq_bf, qw_bf, q_b, q, nullptr, nullptr);
  // alpha logits, softmax over tokens, q_global pool
  logits_kernel<<<512, 256, 0, stream>>>(q, wq_w, wq_b, al);
  pool_kernel<<<128, 512, 0, stream>>>(al, q, qg);
  // p = (x_kv @ k_w^T + k_b) * q_global
  gemm_bf16<1><<<gg, gb, 0, stream>>>(xkv_bf, kw_bf, k_b, p, nullptr, qg);
  // beta logits, softmax, k_global pool
  logits_kernel<<<512, 256, 0, stream>>>(p, wk_w, wk_b, al);
  pool_kernel<<<128, 512, 0, stream>>>(al, p, kglob);
  // u = (x_kv @ v_w^T + v_b) * k_global  -> bf16 directly (only out-proj reads it)
  gemm_bf16<3><<<gg, gb, 0, stream>>>(xkv_bf, vw_bf, v_b, nullptr, u_bf, kglob);
  // out = q + (u @ out_w^T + out_b)
  gemm_bf16<2><<<gg, gb, 0, stream>>>(u_bf, ow_bf, out_b, out, nullptr, q);
}

// Round 3
// 1032.119 us; speedup vs baseline: 1.4437x; 1.4437x over previous
//
#include <hip/hip_runtime.h>
#include <cstdint>
#include <cstddef>

#define D_TOK 1024
#define NH 16
#define DH 64
#define BATCH 8
#define SEQ 4096
#define M_TOT (BATCH * SEQ)   // 32768

typedef unsigned short u16;
typedef __attribute__((ext_vector_type(8))) __bf16 bf16x8;
typedef __attribute__((ext_vector_type(4))) float f32x4;

constexpr float INV_SQRT_DH = 0.125f;  // 1/sqrt(64)

__device__ __forceinline__ u16 f32_to_bf16_rne(float f) {
  union { float f; uint32_t u; } c; c.f = f;
  uint32_t r = (c.u + 0x7FFFu + ((c.u >> 16) & 1u)) >> 16;
  return (u16)r;
}

// ---------------------------------------------------------------------------
// fp32 -> bf16 conversion (RNE), float4 -> ushort4.
// ---------------------------------------------------------------------------
__global__ __launch_bounds__(256) void cvt_f32_bf16(
    const float* __restrict__ in, u16* __restrict__ out, int n4) {
  int i = blockIdx.x * 256 + threadIdx.x;
  const int stride = gridDim.x * 256;
  for (; i < n4; i += stride) {
    const float4 v = reinterpret_cast<const float4*>(in)[i];
    ushort4 o;
    o.x = f32_to_bf16_rne(v.x);
    o.y = f32_to_bf16_rne(v.y);
    o.z = f32_to_bf16_rne(v.z);
    o.w = f32_to_bf16_rne(v.w);
    reinterpret_cast<ushort4*>(out)[i] = o;
  }
}

// ---------------------------------------------------------------------------
// bf16 MFMA GEMM, 256x256 tile, BK=64, 512 threads (8 waves 2Mx4N),
// explicit 2-phase LDS double-buffer (T3 minimum recipe):
//   prologue: STAGE(buf0, t=0); sync;
//   loop t:   STAGE(buf^1, t+1); compute buf; sync;   (one barrier per K-tile)
// LDS: chunked layout [kchunk][row][8] per buffer -> measured 0 bank conflicts
// and linear in global_load_lds write order (base + lane*16).
// MODE 0: C = acc+bias (f32)    MODE 1: C=(acc+bias)*aux[b*1024+n] (f32)
// MODE 2: C = acc+bias+aux[m*1024+n] (f32, residual)
// MODE 3: Cb = bf16((acc+bias)*aux[b*1024+n])
// ---------------------------------------------------------------------------
template <int MODE>
__global__ __launch_bounds__(512, 2) void gemm_bf16(
    const u16* __restrict__ A, const u16* __restrict__ W,
    const float* __restrict__ bias, float* __restrict__ C,
    u16* __restrict__ Cb, const float* __restrict__ aux) {
  // 2 buffers x 2048 chunks x 16B = 32 KB each array half -> 128 KB total
  __shared__ u16 Abuf[2][8 * 256 * 8];
  __shared__ u16 Bbuf[2][8 * 256 * 8];

  const int tid = threadIdx.x;
  const int lane = tid & 63;
  const int wid = tid >> 6;        // 8 waves
  const int wr = wid >> 2;         // 0..1 : 128-row half
  const int wc = wid & 3;          // 0..3 : 64-col quarter
  const int lr = lane & 15;
  const int kg = lane >> 4;        // 0..3

  // 1D grid of 512 wgs; XCD-chunked swizzle (512%8==0 -> bijective),
  // n-fastest decode so the 4 blocks sharing an A-panel are adjacent.
  const int wg = blockIdx.x;
  const int swz = (wg & 7) * 64 + (wg >> 3);
  const int bm0 = (swz >> 2) * 256;
  const int bn0 = (swz & 3) * 256;
  const int b = bm0 >> 12;         // batch index (SEQ=4096)

  f32x4 acc[8][4];
#pragma unroll
  for (int i = 0; i < 8; i++)
#pragma unroll
    for (int j = 0; j < 4; j++) acc[i][j] = (f32x4)0.f;

  // Stage one K-tile (A: 256 rows x 64 k, B: 256 cols x 64 k) into buffer bf.
  auto stage = [&](int bf, int k0) {
#pragma unroll
    for (int i = 0; i < 4; i++) {
      const int c = i * 512 + tid;       // chunk id 0..2047
      const int kc = c >> 8;             // k-chunk 0..7 (8 bf16 each)
      const int r = c & 255;             // row / col 0..255
      const u16* gpA = A + (size_t)(bm0 + r) * D_TOK + k0 + kc * 8;
      const u16* gpB = W + (size_t)(bn0 + r) * D_TOK + k0 + kc * 8;
      u16* ldA = &Abuf[bf][(size_t)(i * 512 + wid * 64) * 8];  // +lane*16B by HW
      u16* ldB = &Bbuf[bf][(size_t)(i * 512 + wid * 64) * 8];
      __builtin_amdgcn_global_load_lds(
          (const __attribute__((address_space(1))) void*)gpA,
          (__attribute__((address_space(3))) void*)ldA, 16, 0, 0);
      __builtin_amdgcn_global_load_lds(
          (const __attribute__((address_space(1))) void*)gpB,
          (__attribute__((address_space(3))) void*)ldB, 16, 0, 0);
    }
  };

  stage(0, 0);
  __syncthreads();  // vmcnt(0) drain + barrier: buf0 ready

  for (int t = 0; t < 16; t++) {
    const int cur = t & 1;
    if (t < 15) stage(cur ^ 1, (t + 1) * 64);  // prefetch next tile
#pragma unroll
    for (int kk = 0; kk < 2; kk++) {
      const int kc = kk * 4 + kg;
      bf16x8 af[8], bv[4];
#pragma unroll
      for (int mi = 0; mi < 8; mi++)
        af[mi] = *reinterpret_cast<const bf16x8*>(
            &Abuf[cur][(size_t)(kc * 256 + wr * 128 + mi * 16 + lr) * 8]);
#pragma unroll
      for (int ni = 0; ni < 4; ni++)
        bv[ni] = *reinterpret_cast<const bf16x8*>(
            &Bbuf[cur][(size_t)(kc * 256 + wc * 64 + ni * 16 + lr) * 8]);
#pragma unroll
      for (int mi = 0; mi < 8; mi++)
#pragma unroll
        for (int ni = 0; ni < 4; ni++)
          acc[mi][ni] = __builtin_amdgcn_mfma_f32_16x16x32_bf16(
              af[mi], bv[ni], acc[mi][ni], 0, 0, 0);
    }
    __syncthreads();  // drains this wave's prefetch loads + barrier
  }

  // Epilogue. D layout: col = lane&15, row = (lane>>4)*4 + reg  [m89/m91]
  float biasv[4], scv[4];
#pragma unroll
  for (int ni = 0; ni < 4; ni++) {
    const int n = bn0 + wc * 64 + ni * 16 + lr;
    biasv[ni] = bias[n];
    if (MODE == 1 || MODE == 3) scv[ni] = aux[(size_t)b * D_TOK + n];
  }
#pragma unroll
  for (int mi = 0; mi < 8; mi++) {
#pragma unroll
    for (int reg = 0; reg < 4; reg++) {
      const int m = bm0 + wr * 128 + mi * 16 + kg * 4 + reg;
#pragma unroll
      for (int ni = 0; ni < 4; ni++) {
        const int n = bn0 + wc * 64 + ni * 16 + lr;
        float o = acc[mi][ni][reg] + biasv[ni];
        if (MODE == 1 || MODE == 3) o *= scv[ni];
        if (MODE == 2) o += aux[(size_t)m * D_TOK + n];
        if (MODE == 3)
          Cb[(size_t)m * D_TOK + n] = f32_to_bf16_rne(o);
        else
          C[(size_t)m * D_TOK + n] = o;
      }
    }
  }
}

// ---------------------------------------------------------------------------
// alpha[t,h] = (dot(src[t,:], w[h,:]) + bias[h]) * inv_sqrt_dh
// One token per wave; W (16x1024 = 64KB) in LDS; float4 loads.
// ---------------------------------------------------------------------------
__global__ __launch_bounds__(256) void logits_kernel(
    const float* __restrict__ src, const float* __restrict__ w,
    const float* __restrict__ bias, float* __restrict__ alpha) {
  __shared__ float Wl[NH * D_TOK];  // 64 KB
  for (int i = threadIdx.x; i < NH * D_TOK / 4; i += 256)
    reinterpret_cast<float4*>(Wl)[i] = reinterpret_cast<const float4*>(w)[i];
  __syncthreads();

  const int lane = threadIdx.x & 63;
  const int wid = threadIdx.x >> 6;  // 4 waves per block
  for (int t = blockIdx.x * 4 + wid; t < M_TOT; t += gridDim.x * 4) {
    const float* row = src + (size_t)t * D_TOK;
    float acc[NH];
#pragma unroll
    for (int h = 0; h < NH; h++) acc[h] = 0.f;
#pragma unroll
    for (int i = 0; i < D_TOK / 256; i++) {  // 4 iters of float4
      const float4 x =
          *reinterpret_cast<const float4*>(&row[lane * 4 + i * 256]);
#pragma unroll
      for (int h = 0; h < NH; h++) {
        const float4 wv = *reinterpret_cast<const float4*>(
            &Wl[h * D_TOK + lane * 4 + i * 256]);
        acc[h] += x.x * wv.x + x.y * wv.y + x.z * wv.z + x.w * wv.w;
      }
    }
#pragma unroll
    for (int h = 0; h < NH; h++) {
      float v = acc[h];
#pragma unroll
      for (int off = 32; off; off >>= 1) v += __shfl_xor(v, off, 64);
      acc[h] = v;
    }
    if (lane == 0) {
#pragma unroll
      for (int h = 0; h < NH; h++)
        alpha[(size_t)t * NH + h] = (acc[h] + bias[h]) * INV_SQRT_DH;
    }
  }
}

// ---------------------------------------------------------------------------
// Per-(b,h): max over tokens + 1/sum(exp). One block per (b,h), 256 thr.
// ---------------------------------------------------------------------------
__global__ __launch_bounds__(256) void softmax_prep(
    const float* __restrict__ al, float* __restrict__ smx,
    float* __restrict__ sinv) {
  __shared__ float red[4];
  const int b = blockIdx.x >> 4, h = blockIdx.x & 15;
  const int tid = threadIdx.x, lane = tid & 63, wid = tid >> 6;
  const float* col = al + (size_t)b * SEQ * NH + h;

  float mx = -INFINITY;
  for (int t = tid; t < SEQ; t += 256) mx = fmaxf(mx, col[(size_t)t * NH]);
#pragma unroll
  for (int off = 32; off; off >>= 1) mx = fmaxf(mx, __shfl_xor(mx, off, 64));
  if (lane == 0) red[wid] = mx;
  __syncthreads();
  mx = fmaxf(fmaxf(red[0], red[1]), fmaxf(red[2], red[3]));
  __syncthreads();

  float s = 0.f;
  for (int t = tid; t < SEQ; t += 256) s += __expf(col[(size_t)t * NH] - mx);
#pragma unroll
  for (int off = 32; off; off >>= 1) s += __shfl_xor(s, off, 64);
  if (lane == 0) red[wid] = s;
  __syncthreads();
  if (tid == 0) {
    const float tot = red[0] + red[1] + red[2] + red[3];
    smx[blockIdx.x] = mx;
    sinv[blockIdx.x] = 1.0f / tot;
  }
}

// ---------------------------------------------------------------------------
// g[b,d] += sum_{t in chunk} exp(al[b,t,h(d)]-mx)*inv * src[b,t,d]
// Grid: BATCH * (SEQ/64) blocks, 256 thr; thread owns 4 consecutive d.
// Fully-coalesced float4 row streaming; fp32 atomicAdd into g (pre-zeroed).
// ---------------------------------------------------------------------------
__global__ __launch_bounds__(256) void pool_accum(
    const float* __restrict__ al, const float* __restrict__ src,
    const float* __restrict__ smx, const float* __restrict__ sinv,
    float* __restrict__ g) {
  constexpr int TCH = 64;
  const int b = blockIdx.x / (SEQ / TCH);
  const int t0 = (blockIdx.x % (SEQ / TCH)) * TCH;
  const int d0 = threadIdx.x * 4;
  const int h = d0 >> 6;
  const float mx = smx[b * NH + h];
  const float inv = sinv[b * NH + h];

  float4 acc = make_float4(0.f, 0.f, 0.f, 0.f);
  const float* ap = al + ((size_t)b * SEQ + t0) * NH + h;
  const float* sp = src + ((size_t)b * SEQ + t0) * D_TOK + d0;
#pragma unroll 2
  for (int t = 0; t < TCH; t++) {
    const float wgt = __expf(ap[(size_t)t * NH] - mx) * inv;
    const float4 v = *reinterpret_cast<const float4*>(sp + (size_t)t * D_TOK);
    acc.x += wgt * v.x;
    acc.y += wgt * v.y;
    acc.z += wgt * v.z;
    acc.w += wgt * v.w;
  }
  float* gp = g + (size_t)b * D_TOK + d0;
  atomicAdd(gp + 0, acc.x);
  atomicAdd(gp + 1, acc.y);
  atomicAdd(gp + 2, acc.z);
  atomicAdd(gp + 3, acc.w);
}

// ---------------------------------------------------------------------------
extern "C" void kernel_launch(void* const* d_in, const int* in_sizes, int n_in,
                              void* d_out, int out_size, void* d_ws,
                              size_t ws_size, hipStream_t stream) {
  const float* x_q   = (const float*)d_in[0];
  const float* x_kv  = (const float*)d_in[1];
  const float* q_w   = (const float*)d_in[2];
  const float* k_w   = (const float*)d_in[3];
  const float* v_w   = (const float*)d_in[4];
  const float* wq_w  = (const float*)d_in[5];
  const float* wk_w  = (const float*)d_in[6];
  const float* out_w = (const float*)d_in[7];
  const float* q_b   = (const float*)d_in[8];
  const float* k_b   = (const float*)d_in[9];
  const float* v_b   = (const float*)d_in[10];
  const float* wq_b  = (const float*)d_in[11];
  const float* wk_b  = (const float*)d_in[12];
  const float* out_b = (const float*)d_in[13];
  float* out = (float*)d_out;

  char* ws = (char*)d_ws;
  const size_t SZ_F32 = (size_t)M_TOT * D_TOK * sizeof(float);  // 128 MiB
  const size_t SZ_BF  = (size_t)M_TOT * D_TOK * sizeof(u16);    // 64 MiB
  const size_t SZ_WBF = (size_t)D_TOK * D_TOK * sizeof(u16);    // 2 MiB
  size_t off = 0;
  float* q      = (float*)(ws + off); off += SZ_F32;
  float* p      = (float*)(ws + off); off += SZ_F32;
  u16*   xq_bf  = (u16*)(ws + off);   off += SZ_BF;   // reused as u_bf
  u16*   xkv_bf = (u16*)(ws + off);   off += SZ_BF;
  u16*   qw_bf  = (u16*)(ws + off);   off += SZ_WBF;
  u16*   kw_bf  = (u16*)(ws + off);   off += SZ_WBF;
  u16*   vw_bf  = (u16*)(ws + off);   off += SZ_WBF;
  u16*   ow_bf  = (u16*)(ws + off);   off += SZ_WBF;
  float* al     = (float*)(ws + off); off += (size_t)M_TOT * NH * sizeof(float);
  float* qg     = (float*)(ws + off); off += (size_t)BATCH * D_TOK * sizeof(float);
  float* kglob  = (float*)(ws + off); off += (size_t)BATCH * D_TOK * sizeof(float);
  float* smx0   = (float*)(ws + off); off += BATCH * NH * sizeof(float);
  float* sinv0  = (float*)(ws + off); off += BATCH * NH * sizeof(float);
  float* smx1   = (float*)(ws + off); off += BATCH * NH * sizeof(float);
  float* sinv1  = (float*)(ws + off); off += BATCH * NH * sizeof(float);
  u16* u_bf = xq_bf;  // x_q_bf dead after GEMM1; u written by GEMM3

  const int NX4 = M_TOT * D_TOK / 4;
  const int NW4 = D_TOK * D_TOK / 4;

  // zero pooled-vector accumulators (atomicAdd targets)
  hipMemsetAsync(qg, 0, BATCH * D_TOK * sizeof(float), stream);
  hipMemsetAsync(kglob, 0, BATCH * D_TOK * sizeof(float), stream);

  // fp32 -> bf16 conversions
  cvt_f32_bf16<<<2048, 256, 0, stream>>>(x_q,   xq_bf,  NX4);
  cvt_f32_bf16<<<2048, 256, 0, stream>>>(x_kv,  xkv_bf, NX4);
  cvt_f32_bf16<<<512,  256, 0, stream>>>(q_w,   qw_bf,  NW4);
  cvt_f32_bf16<<<512,  256, 0, stream>>>(k_w,   kw_bf,  NW4);
  cvt_f32_bf16<<<512,  256, 0, stream>>>(v_w,   vw_bf,  NW4);
  cvt_f32_bf16<<<512,  256, 0, stream>>>(out_w, ow_bf,  NW4);

  const dim3 gg(512), gb(512);  // 128 M-panels x 4 N-panels
  const dim3 pg(BATCH * (SEQ / 64)), pb(256);

  // q = x_q @ q_w^T + q_b
  gemm_bf16<0><<<gg, gb, 0, stream>>>(xq_bf, qw_bf, q_b, q, nullptr, nullptr);
  // alpha logits -> softmax prep -> q_global pool
  logits_kernel<<<512, 256, 0, stream>>>(q, wq_w, wq_b, al);
  softmax_prep<<<BATCH * NH, 256, 0, stream>>>(al, smx0, sinv0);
  pool_accum<<<pg, pb, 0, stream>>>(al, q, smx0, sinv0, qg);
  // p = (x_kv @ k_w^T + k_b) * q_global
  gemm_bf16<1><<<gg, gb, 0, stream>>>(xkv_bf, kw_bf, k_b, p, nullptr, qg);
  // beta logits -> softmax prep -> k_global pool
  logits_kernel<<<512, 256, 0, stream>>>(p, wk_w, wk_b, al);
  softmax_prep<<<BATCH * NH, 256, 0, stream>>>(al, smx1, sinv1);
  pool_accum<<<pg, pb, 0, stream>>>(al, p, smx1, sinv1, kglob);
  // u = (x_kv @ v_w^T + v_b) * k_global -> bf16 (only out-proj reads it)
  gemm_bf16<3><<<gg, gb, 0, stream>>>(xkv_bf, vw_bf, v_b, nullptr, u_bf, kglob);
  // out = q + (u @ out_w^T + out_b)
  gemm_bf16<2><<<gg, gb, 0, stream>>>(u_bf, ow_bf, out_b, out, nullptr, q);
}

// Round 4
// 965.780 us; speedup vs baseline: 1.5429x; 1.0687x over previous
//
#include <hip/hip_runtime.h>
#include <cstdint>
#include <cstddef>

#define D_TOK 1024
#define NH 16
#define DH 64
#define BATCH 8
#define SEQ 4096
#define M_TOT (BATCH * SEQ)   // 32768

typedef unsigned short u16;
typedef __attribute__((ext_vector_type(8))) __bf16 bf16x8;
typedef __attribute__((ext_vector_type(4))) float f32x4;

constexpr float INV_SQRT_DH = 0.125f;  // 1/sqrt(64)

__device__ __forceinline__ u16 f32_to_bf16_rne(float f) {
  union { float f; uint32_t u; } c; c.f = f;
  uint32_t r = (c.u + 0x7FFFu + ((c.u >> 16) & 1u)) >> 16;
  return (u16)r;
}
__device__ __forceinline__ float bf2f(u16 u) {
  union { uint32_t i; float f; } c;
  c.i = (uint32_t)u << 16;
  return c.f;
}

// ---------------------------------------------------------------------------
// fp32 -> bf16 conversion (RNE), float4 -> ushort4.
// ---------------------------------------------------------------------------
__global__ __launch_bounds__(256) void cvt_f32_bf16(
    const float* __restrict__ in, u16* __restrict__ out, int n4) {
  int i = blockIdx.x * 256 + threadIdx.x;
  const int stride = gridDim.x * 256;
  for (; i < n4; i += stride) {
    const float4 v = reinterpret_cast<const float4*>(in)[i];
    ushort4 o;
    o.x = f32_to_bf16_rne(v.x);
    o.y = f32_to_bf16_rne(v.y);
    o.z = f32_to_bf16_rne(v.z);
    o.w = f32_to_bf16_rne(v.w);
    reinterpret_cast<ushort4*>(out)[i] = o;
  }
}

// ---------------------------------------------------------------------------
// bf16 MFMA GEMM, 256x256 tile, BK=64, 512 thr (8 waves 2Mx4N).
// Counted-vmcnt 3-deep pipeline (T3+T4): 2 staged K-tiles always in flight,
// main-loop waits are vmcnt(8) — never a full drain. Raw s_barrier + manual
// waits; sched_barrier(0) after each asm wait (rule 18).
//   per iter: vmcnt(8); bar; ds_read kk0; MFMA kk0; ds_read kk1;
//             lgkmcnt(0); bar; stage(t+2); setprio1 MFMA kk1 setprio0
// LDS chunked layout [kchunk][row][8]: 0 measured bank conflicts, linear in
// global_load_lds write order.
// MODE 0: C=acc+bias (f32)        MODE 1: C=(acc+bias)*aux[b*1024+n] (f32)
// MODE 2: C=acc+bias+aux[m*1024+n] (f32 residual)
// MODE 3: Cb=bf16((acc+bias)*aux[b*1024+n])
// MODE 4: C=acc+bias (f32) AND Cb=bf16(same)
// ---------------------------------------------------------------------------
template <int MODE>
__global__ __launch_bounds__(512, 2) void gemm_bf16(
    const u16* __restrict__ A, const u16* __restrict__ W,
    const float* __restrict__ bias, float* __restrict__ C,
    u16* __restrict__ Cb, const float* __restrict__ aux) {
  __shared__ u16 Abuf[2][8 * 256 * 8];  // 64 KB
  __shared__ u16 Bbuf[2][8 * 256 * 8];  // 64 KB

  const int tid = threadIdx.x;
  const int lane = tid & 63;
  const int wid = tid >> 6;        // 8 waves
  const int wr = wid >> 2;         // 0..1 : 128-row half
  const int wc = wid & 3;          // 0..3 : 64-col quarter
  const int lr = lane & 15;
  const int kg = lane >> 4;        // 0..3

  // XCD-chunked bijective swizzle (512 % 8 == 0); n-fastest decode.
  const int wg = blockIdx.x;
  const int swz = (wg & 7) * 64 + (wg >> 3);
  const int bm0 = (swz >> 2) * 256;
  const int bn0 = (swz & 3) * 256;
  const int b = bm0 >> 12;         // batch index (SEQ=4096)

  f32x4 acc[8][4];
#pragma unroll
  for (int i = 0; i < 8; i++)
#pragma unroll
    for (int j = 0; j < 4; j++) acc[i][j] = (f32x4)0.f;

  // Stage one K-tile (A: 256 rows x 64 k, B: 256 cols x 64 k); 8 loads/wave.
  auto stage = [&](int bf, int k0) {
#pragma unroll
    for (int i = 0; i < 4; i++) {
      const int c = i * 512 + tid;       // chunk id 0..2047
      const int kc = c >> 8;             // k-chunk 0..7 (8 bf16)
      const int r = c & 255;             // row / col
      const u16* gpA = A + (size_t)(bm0 + r) * D_TOK + k0 + kc * 8;
      const u16* gpB = W + (size_t)(bn0 + r) * D_TOK + k0 + kc * 8;
      u16* ldA = &Abuf[bf][(size_t)(i * 512 + wid * 64) * 8];  // +lane*16B HW
      u16* ldB = &Bbuf[bf][(size_t)(i * 512 + wid * 64) * 8];
      __builtin_amdgcn_global_load_lds(
          (const __attribute__((address_space(1))) void*)gpA,
          (__attribute__((address_space(3))) void*)ldA, 16, 0, 0);
      __builtin_amdgcn_global_load_lds(
          (const __attribute__((address_space(1))) void*)gpB,
          (__attribute__((address_space(3))) void*)ldB, 16, 0, 0);
    }
  };

  stage(0, 0);     // 8 loads in flight
  stage(1, 64);    // 16 in flight

  for (int t = 0; t < 16; ++t) {
    const int cur = t & 1;
    // tile t landed; keep tile t+1's 8 loads flying
    if (t < 15) {
      asm volatile("s_waitcnt vmcnt(8)" ::: "memory");
    } else {
      asm volatile("s_waitcnt vmcnt(0)" ::: "memory");
    }
    __builtin_amdgcn_sched_barrier(0);
    __builtin_amdgcn_s_barrier();

    bf16x8 af0[8], bv0[4], af1[8], bv1[4];
#pragma unroll
    for (int mi = 0; mi < 8; mi++)
      af0[mi] = *reinterpret_cast<const bf16x8*>(
          &Abuf[cur][(size_t)(kg * 256 + wr * 128 + mi * 16 + lr) * 8]);
#pragma unroll
    for (int ni = 0; ni < 4; ni++)
      bv0[ni] = *reinterpret_cast<const bf16x8*>(
          &Bbuf[cur][(size_t)(kg * 256 + wc * 64 + ni * 16 + lr) * 8]);
#pragma unroll
    for (int mi = 0; mi < 8; mi++)
#pragma unroll
      for (int ni = 0; ni < 4; ni++)
        acc[mi][ni] = __builtin_amdgcn_mfma_f32_16x16x32_bf16(
            af0[mi], bv0[ni], acc[mi][ni], 0, 0, 0);
#pragma unroll
    for (int mi = 0; mi < 8; mi++)
      af1[mi] = *reinterpret_cast<const bf16x8*>(
          &Abuf[cur][(size_t)((4 + kg) * 256 + wr * 128 + mi * 16 + lr) * 8]);
#pragma unroll
    for (int ni = 0; ni < 4; ni++)
      bv1[ni] = *reinterpret_cast<const bf16x8*>(
          &Bbuf[cur][(size_t)((4 + kg) * 256 + wc * 64 + ni * 16 + lr) * 8]);
    // all this wave's reads of buf[cur] complete -> safe to restage after bar
    asm volatile("s_waitcnt lgkmcnt(0)" ::: "memory");
    __builtin_amdgcn_sched_barrier(0);
    __builtin_amdgcn_s_barrier();
    if (t < 14) stage(cur, (t + 2) * 64);  // 8 more loads; back to 16 in flight
    __builtin_amdgcn_s_setprio(1);
#pragma unroll
    for (int mi = 0; mi < 8; mi++)
#pragma unroll
      for (int ni = 0; ni < 4; ni++)
        acc[mi][ni] = __builtin_amdgcn_mfma_f32_16x16x32_bf16(
            af1[mi], bv1[ni], acc[mi][ni], 0, 0, 0);
    __builtin_amdgcn_s_setprio(0);
  }

  // Epilogue. D layout: col = lane&15, row = (lane>>4)*4 + reg  [m89/m91]
  float biasv[4], scv[4];
#pragma unroll
  for (int ni = 0; ni < 4; ni++) {
    const int n = bn0 + wc * 64 + ni * 16 + lr;
    biasv[ni] = bias[n];
    if (MODE == 1 || MODE == 3) scv[ni] = aux[(size_t)b * D_TOK + n];
  }
#pragma unroll
  for (int mi = 0; mi < 8; mi++) {
#pragma unroll
    for (int reg = 0; reg < 4; reg++) {
      const int m = bm0 + wr * 128 + mi * 16 + kg * 4 + reg;
#pragma unroll
      for (int ni = 0; ni < 4; ni++) {
        const int n = bn0 + wc * 64 + ni * 16 + lr;
        float o = acc[mi][ni][reg] + biasv[ni];
        if (MODE == 1 || MODE == 3) o *= scv[ni];
        if (MODE == 2) o += aux[(size_t)m * D_TOK + n];
        if (MODE == 3) {
          Cb[(size_t)m * D_TOK + n] = f32_to_bf16_rne(o);
        } else if (MODE == 4) {
          C[(size_t)m * D_TOK + n] = o;
          Cb[(size_t)m * D_TOK + n] = f32_to_bf16_rne(o);
        } else {
          C[(size_t)m * D_TOK + n] = o;
        }
      }
    }
  }
}

// ---------------------------------------------------------------------------
// alpha[t,h] = (dot(src[t,:], w[h,:]) + bias[h]) * inv_sqrt_dh ; src is bf16.
// One token per wave; W (16x1024 f32 = 64KB) in LDS, stride-1 reads (2-way,
// free). Scalar bf16 global loads: 64 lanes x 2B contiguous = coalesced.
// ---------------------------------------------------------------------------
__global__ __launch_bounds__(256) void logits_bf(
    const u16* __restrict__ src, const float* __restrict__ w,
    const float* __restrict__ bias, float* __restrict__ alpha) {
  __shared__ float Wl[NH * D_TOK];  // 64 KB
  for (int i = threadIdx.x; i < NH * D_TOK / 4; i += 256)
    reinterpret_cast<float4*>(Wl)[i] = reinterpret_cast<const float4*>(w)[i];
  __syncthreads();

  const int lane = threadIdx.x & 63;
  const int wid = threadIdx.x >> 6;
  for (int t = blockIdx.x * 4 + wid; t < M_TOT; t += gridDim.x * 4) {
    const u16* row = src + (size_t)t * D_TOK;
    float acc[NH];
#pragma unroll
    for (int h = 0; h < NH; h++) acc[h] = 0.f;
#pragma unroll 4
    for (int i = 0; i < D_TOK / 64; i++) {
      const float x = bf2f(row[lane + i * 64]);
#pragma unroll
      for (int h = 0; h < NH; h++) acc[h] += x * Wl[h * D_TOK + lane + i * 64];
    }
#pragma unroll
    for (int h = 0; h < NH; h++) {
      float v = acc[h];
#pragma unroll
      for (int off = 32; off; off >>= 1) v += __shfl_xor(v, off, 64);
      acc[h] = v;
    }
    if (lane == 0) {
#pragma unroll
      for (int h = 0; h < NH; h++)
        alpha[(size_t)t * NH + h] = (acc[h] + bias[h]) * INV_SQRT_DH;
    }
  }
}

// ---------------------------------------------------------------------------
// Per-(b,h): max over tokens + 1/sum(exp). One block per (b,h), 256 thr.
// ---------------------------------------------------------------------------
__global__ __launch_bounds__(256) void softmax_prep(
    const float* __restrict__ al, float* __restrict__ smx,
    float* __restrict__ sinv) {
  __shared__ float red[4];
  const int b = blockIdx.x >> 4, h = blockIdx.x & 15;
  const int tid = threadIdx.x, lane = tid & 63, wid = tid >> 6;
  const float* col = al + (size_t)b * SEQ * NH + h;

  float mx = -INFINITY;
  for (int t = tid; t < SEQ; t += 256) mx = fmaxf(mx, col[(size_t)t * NH]);
#pragma unroll
  for (int off = 32; off; off >>= 1) mx = fmaxf(mx, __shfl_xor(mx, off, 64));
  if (lane == 0) red[wid] = mx;
  __syncthreads();
  mx = fmaxf(fmaxf(red[0], red[1]), fmaxf(red[2], red[3]));
  __syncthreads();

  float s = 0.f;
  for (int t = tid; t < SEQ; t += 256) s += __expf(col[(size_t)t * NH] - mx);
#pragma unroll
  for (int off = 32; off; off >>= 1) s += __shfl_xor(s, off, 64);
  if (lane == 0) red[wid] = s;
  __syncthreads();
  if (tid == 0) {
    const float tot = red[0] + red[1] + red[2] + red[3];
    smx[blockIdx.x] = mx;
    sinv[blockIdx.x] = 1.0f / tot;
  }
}

// ---------------------------------------------------------------------------
// g[b,d] += sum_{t in chunk} exp(al[b,t,h(d)]-mx)*inv * src_bf16[b,t,d]
// Grid: BATCH*(SEQ/64) blocks, 256 thr; thread owns 4 consecutive d.
// ---------------------------------------------------------------------------
__global__ __launch_bounds__(256) void pool_accum_bf(
    const float* __restrict__ al, const u16* __restrict__ src,
    const float* __restrict__ smx, const float* __restrict__ sinv,
    float* __restrict__ g) {
  constexpr int TCH = 64;
  const int b = blockIdx.x / (SEQ / TCH);
  const int t0 = (blockIdx.x % (SEQ / TCH)) * TCH;
  const int d0 = threadIdx.x * 4;
  const int h = d0 >> 6;
  const float mx = smx[b * NH + h];
  const float inv = sinv[b * NH + h];

  float4 acc = make_float4(0.f, 0.f, 0.f, 0.f);
  const float* ap = al + ((size_t)b * SEQ + t0) * NH + h;
  const u16* sp = src + ((size_t)b * SEQ + t0) * D_TOK + d0;
#pragma unroll 2
  for (int t = 0; t < TCH; t++) {
    const float wgt = __expf(ap[(size_t)t * NH] - mx) * inv;
    const ushort4 v = *reinterpret_cast<const ushort4*>(sp + (size_t)t * D_TOK);
    acc.x += wgt * bf2f(v.x);
    acc.y += wgt * bf2f(v.y);
    acc.z += wgt * bf2f(v.z);
    acc.w += wgt * bf2f(v.w);
  }
  float* gp = g + (size_t)b * D_TOK + d0;
  atomicAdd(gp + 0, acc.x);
  atomicAdd(gp + 1, acc.y);
  atomicAdd(gp + 2, acc.z);
  atomicAdd(gp + 3, acc.w);
}

// ---------------------------------------------------------------------------
extern "C" void kernel_launch(void* const* d_in, const int* in_sizes, int n_in,
                              void* d_out, int out_size, void* d_ws,
                              size_t ws_size, hipStream_t stream) {
  const float* x_q   = (const float*)d_in[0];
  const float* x_kv  = (const float*)d_in[1];
  const float* q_w   = (const float*)d_in[2];
  const float* k_w   = (const float*)d_in[3];
  const float* v_w   = (const float*)d_in[4];
  const float* wq_w  = (const float*)d_in[5];
  const float* wk_w  = (const float*)d_in[6];
  const float* out_w = (const float*)d_in[7];
  const float* q_b   = (const float*)d_in[8];
  const float* k_b   = (const float*)d_in[9];
  const float* v_b   = (const float*)d_in[10];
  const float* wq_b  = (const float*)d_in[11];
  const float* wk_b  = (const float*)d_in[12];
  const float* out_b = (const float*)d_in[13];
  float* out = (float*)d_out;

  char* ws = (char*)d_ws;
  const size_t SZ_F32 = (size_t)M_TOT * D_TOK * sizeof(float);  // 128 MiB
  const size_t SZ_BF  = (size_t)M_TOT * D_TOK * sizeof(u16);    // 64 MiB
  const size_t SZ_WBF = (size_t)D_TOK * D_TOK * sizeof(u16);    // 2 MiB
  size_t off = 0;
  float* q      = (float*)(ws + off); off += SZ_F32;   // q f32 (residual)
  char*  pbase  = ws + off;           off += SZ_F32;   // 128 MiB scratch:
  u16*   p_bf   = (u16*)pbase;                          //  first 64 MiB
  u16*   q_bf   = (u16*)(pbase + SZ_BF);                //  second 64 MiB
  u16*   xq_bf  = (u16*)(ws + off);   off += SZ_BF;    // reused as u_bf
  u16*   xkv_bf = (u16*)(ws + off);   off += SZ_BF;
  u16*   qw_bf  = (u16*)(ws + off);   off += SZ_WBF;
  u16*   kw_bf  = (u16*)(ws + off);   off += SZ_WBF;
  u16*   vw_bf  = (u16*)(ws + off);   off += SZ_WBF;
  u16*   ow_bf  = (u16*)(ws + off);   off += SZ_WBF;
  float* al     = (float*)(ws + off); off += (size_t)M_TOT * NH * sizeof(float);
  float* qg     = (float*)(ws + off); off += (size_t)BATCH * D_TOK * sizeof(float);
  float* kglob  = (float*)(ws + off); off += (size_t)BATCH * D_TOK * sizeof(float);
  float* smx0   = (float*)(ws + off); off += BATCH * NH * sizeof(float);
  float* sinv0  = (float*)(ws + off); off += BATCH * NH * sizeof(float);
  float* smx1   = (float*)(ws + off); off += BATCH * NH * sizeof(float);
  float* sinv1  = (float*)(ws + off); off += BATCH * NH * sizeof(float);
  u16* u_bf = xq_bf;  // x_q_bf dead after GEMM0; u written by GEMM2

  const int NX4 = M_TOT * D_TOK / 4;
  const int NW4 = D_TOK * D_TOK / 4;

  hipMemsetAsync(qg, 0, BATCH * D_TOK * sizeof(float), stream);
  hipMemsetAsync(kglob, 0, BATCH * D_TOK * sizeof(float), stream);

  cvt_f32_bf16<<<2048, 256, 0, stream>>>(x_q,   xq_bf,  NX4);
  cvt_f32_bf16<<<2048, 256, 0, stream>>>(x_kv,  xkv_bf, NX4);
  cvt_f32_bf16<<<512,  256, 0, stream>>>(q_w,   qw_bf,  NW4);
  cvt_f32_bf16<<<512,  256, 0, stream>>>(k_w,   kw_bf,  NW4);
  cvt_f32_bf16<<<512,  256, 0, stream>>>(v_w,   vw_bf,  NW4);
  cvt_f32_bf16<<<512,  256, 0, stream>>>(out_w, ow_bf,  NW4);

  const dim3 gg(512), gb(512);  // 128 M-panels x 4 N-panels
  const dim3 pg(BATCH * (SEQ / 64)), pb(256);

  // q = x_q @ q_w^T + q_b   (f32 + bf16 dual write)
  gemm_bf16<4><<<gg, gb, 0, stream>>>(xq_bf, qw_bf, q_b, q, q_bf, nullptr);
  // alpha logits -> softmax prep -> q_global pool (bf16 reads)
  logits_bf<<<512, 256, 0, stream>>>(q_bf, wq_w, wq_b, al);
  softmax_prep<<<BATCH * NH, 256, 0, stream>>>(al, smx0, sinv0);
  pool_accum_bf<<<pg, pb, 0, stream>>>(al, q_bf, smx0, sinv0, qg);
  // p = (x_kv @ k_w^T + k_b) * q_global   (bf16 out)
  gemm_bf16<3><<<gg, gb, 0, stream>>>(xkv_bf, kw_bf, k_b, nullptr, p_bf, qg);
  // beta logits -> softmax prep -> k_global pool
  logits_bf<<<512, 256, 0, stream>>>(p_bf, wk_w, wk_b, al);
  softmax_prep<<<BATCH * NH, 256, 0, stream>>>(al, smx1, sinv1);
  pool_accum_bf<<<pg, pb, 0, stream>>>(al, p_bf, smx1, sinv1, kglob);
  // u = (x_kv @ v_w^T + v_b) * k_global  (bf16 out)
  gemm_bf16<3><<<gg, gb, 0, stream>>>(xkv_bf, vw_bf, v_b, nullptr, u_bf, kglob);
  // out = q + (u @ out_w^T + out_b)
  gemm_bf16<2><<<gg, gb, 0, stream>>>(u_bf, ow_bf, out_b, out, nullptr, q);
}

// Round 5
// 768.461 us; speedup vs baseline: 1.9391x; 1.2568x over previous
//
#include <hip/hip_runtime.h>
#include <cstdint>
#include <cstddef>

#define D_TOK 1024
#define NH 16
#define DH 64
#define BATCH 8
#define SEQ 4096
#define M_TOT (BATCH * SEQ)   // 32768

typedef unsigned short u16;
typedef __attribute__((ext_vector_type(8))) __bf16 bf16x8;
typedef __attribute__((ext_vector_type(4))) float f32x4;

constexpr float INV_SQRT_DH = 0.125f;  // 1/sqrt(64)

__device__ __forceinline__ u16 f32_to_bf16_rne(float f) {
  union { float f; uint32_t u; } c; c.f = f;
  uint32_t r = (c.u + 0x7FFFu + ((c.u >> 16) & 1u)) >> 16;
  return (u16)r;
}
__device__ __forceinline__ float bf2f(u16 u) {
  union { uint32_t i; float f; } c;
  c.i = (uint32_t)u << 16;
  return c.f;
}

// ---------------------------------------------------------------------------
// fp32 -> bf16 conversion (RNE), float4 -> ushort4.
// ---------------------------------------------------------------------------
__global__ __launch_bounds__(256) void cvt_f32_bf16(
    const float* __restrict__ in, u16* __restrict__ out, int n4) {
  int i = blockIdx.x * 256 + threadIdx.x;
  const int stride = gridDim.x * 256;
  for (; i < n4; i += stride) {
    const float4 v = reinterpret_cast<const float4*>(in)[i];
    ushort4 o;
    o.x = f32_to_bf16_rne(v.x);
    o.y = f32_to_bf16_rne(v.y);
    o.z = f32_to_bf16_rne(v.z);
    o.w = f32_to_bf16_rne(v.w);
    reinterpret_cast<ushort4*>(out)[i] = o;
  }
}

// ---------------------------------------------------------------------------
// bf16 MFMA GEMM, 256x256 tile, BK=64, 512 thr (8 waves 2Mx4N).
// m201-style 8-phase schedule, 2 K-tiles per iteration, counted vmcnt.
// LDS: 16 quarters of 8KB: Sh[buf][A/B][half128][kk32][512 chunks * 8 bf16],
// chunked layout (kg*128 + row) -> measured 0 bank conflicts, and linear in
// global_load_lds write order (wave-uniform base + lane*16B).
// Stage stream (iter i computes tiles T0=2i in buf0, T1=2i+1 in buf1):
//   p0,p1 -> buf1.kk1 (tile T1)     p2,p3 -> buf0.kk0 (tile T0+2)
//   p4,p5 -> buf0.kk1 (tile T0+2)   p6,p7 -> buf1.kk0 (tile T1+2)
// vmcnt(4) at end of p3 (retires buf1.kk0+kk1) and p7 (retires buf0 full).
// Last iteration: vmcnt(0) at p3; stages beyond tile 15 gated off.
// MODE 0: C=acc+bias (f32)        MODE 1: C=(acc+bias)*aux[b*1024+n] (f32)
// MODE 2: C=acc+bias+aux[m*1024+n] (f32 residual)
// MODE 3: Cb=bf16((acc+bias)*aux)  MODE 4: f32 AND bf16 dual write
// ---------------------------------------------------------------------------
#define DS_READS(BUF, KK, MH)                                                  \
  {                                                                            \
    _Pragma("unroll") for (int j = 0; j < 4; ++j)                              \
        af[j] = *reinterpret_cast<const bf16x8*>(                              \
            &Sh[BUF][0][wr][KK][(kg * 128 + (MH)*64 + j * 16 + lr) * 8]);      \
    if ((MH) == 0) {                                                           \
      _Pragma("unroll") for (int n = 0; n < 4; ++n)                            \
          bv[n] = *reinterpret_cast<const bf16x8*>(                            \
              &Sh[BUF][1][wch][KK][(kg * 128 + wcl * 64 + n * 16 + lr) * 8]);  \
    }                                                                          \
  }

#define MFMA16(MH)                                                             \
  {                                                                            \
    __builtin_amdgcn_s_setprio(1);                                             \
    _Pragma("unroll") for (int j = 0; j < 4; ++j)                              \
        _Pragma("unroll") for (int n = 0; n < 4; ++n)                          \
            acc[(MH)*4 + j][n] = __builtin_amdgcn_mfma_f32_16x16x32_bf16(      \
                af[j], bv[n], acc[(MH)*4 + j][n], 0, 0, 0);                    \
    __builtin_amdgcn_s_setprio(0);                                             \
  }

#define BAR() __builtin_amdgcn_s_barrier()
#define LGKM0()                                              \
  do {                                                       \
    asm volatile("s_waitcnt lgkmcnt(0)" ::: "memory");       \
    __builtin_amdgcn_sched_barrier(0);                       \
  } while (0)
#define VMW(N)                                               \
  do {                                                       \
    asm volatile("s_waitcnt vmcnt(" #N ")" ::: "memory");    \
    __builtin_amdgcn_sched_barrier(0);                       \
  } while (0)

template <int MODE>
__global__ __launch_bounds__(512, 2) void gemm_bf16(
    const u16* __restrict__ A, const u16* __restrict__ W,
    const float* __restrict__ bias, float* __restrict__ C,
    u16* __restrict__ Cb, const float* __restrict__ aux) {
  __shared__ u16 Sh[2][2][2][2][512 * 8];  // 128 KiB

  const int tid = threadIdx.x;
  const int lane = tid & 63;
  const int wid = tid >> 6;        // 8 waves
  const int wr = wid >> 2;         // 0..1 : 128-row half (A half index)
  const int wc = wid & 3;          // 0..3 : 64-col quarter
  const int wch = wc >> 1;         // B half index
  const int wcl = wc & 1;          // 64-col within B half
  const int lr = lane & 15;
  const int kg = lane >> 4;        // 0..3

  // XCD-chunked bijective swizzle (512 % 8 == 0); n-fastest decode.
  const int wg = blockIdx.x;
  const int swz = (wg & 7) * 64 + (wg >> 3);
  const int bm0 = (swz >> 2) * 256;
  const int bn0 = (swz & 3) * 256;
  const int b = bm0 >> 12;         // batch index (SEQ=4096)

  f32x4 acc[8][4];
#pragma unroll
  for (int i = 0; i < 8; i++)
#pragma unroll
    for (int j = 0; j < 4; j++) acc[i][j] = (f32x4)0.f;

  // Stage one 8KB quarter (mat: 0=A,1=B; half: 128 rows; kkq: 32-k half).
  // One global_load_lds per thread; LDS dest wave-uniform base + lane*16B.
  auto stageQ = [&](int buf, int mat, int half, int kkq, int t) {
    if (t > 15) return;
    const int kcl = tid >> 7;          // 0..3 (wave-uniform: wid>>1)
    const int r = tid & 127;           // row within half
    const u16* src = (mat == 0) ? A : W;
    const int base0 = (mat == 0) ? bm0 : bn0;
    const u16* gp = src + (size_t)(base0 + half * 128 + r) * D_TOK +
                    t * 64 + kkq * 32 + kcl * 8;
    u16* ld = &Sh[buf][mat][half][kkq][(size_t)wid * 64 * 8];
    __builtin_amdgcn_global_load_lds(
        (const __attribute__((address_space(1))) void*)gp,
        (__attribute__((address_space(3))) void*)ld, 16, 0, 0);
  };

  // Prologue: tile0 full (8 quarters, oldest) + tile1.kk0 (4 quarters).
  stageQ(0, 0, 0, 0, 0); stageQ(0, 0, 1, 0, 0);
  stageQ(0, 1, 0, 0, 0); stageQ(0, 1, 1, 0, 0);
  stageQ(0, 0, 0, 1, 0); stageQ(0, 0, 1, 1, 0);
  stageQ(0, 1, 0, 1, 0); stageQ(0, 1, 1, 1, 0);
  stageQ(1, 0, 0, 0, 1); stageQ(1, 0, 1, 0, 1);
  stageQ(1, 1, 0, 0, 1); stageQ(1, 1, 1, 0, 1);
  VMW(4);  // tile0 landed; tile1.kk0 (4) still in flight
  BAR();

  bf16x8 bv[4];
  for (int it = 0; it < 8; ++it) {
    const int T1 = 2 * it + 1, T2 = 2 * it + 2, T3 = 2 * it + 3;
    const bool last = (it == 7);
    bf16x8 af[4];
    // p0: compute buf0.kk0.mh0 | stage buf1.kk1 A (tile T1)
    DS_READS(0, 0, 0);
    stageQ(1, 0, 0, 1, T1); stageQ(1, 0, 1, 1, T1);
    BAR(); LGKM0(); MFMA16(0); BAR();
    // p1: buf0.kk0.mh1 | stage buf1.kk1 B
    DS_READS(0, 0, 1);
    stageQ(1, 1, 0, 1, T1); stageQ(1, 1, 1, 1, T1);
    BAR(); LGKM0(); MFMA16(1); BAR();
    // p2: buf0.kk1.mh0 | stage buf0.kk0 A (tile T2)
    DS_READS(0, 1, 0);
    stageQ(0, 0, 0, 0, T2); stageQ(0, 0, 1, 0, T2);
    BAR(); LGKM0(); MFMA16(0); BAR();
    // p3: buf0.kk1.mh1 | stage buf0.kk0 B; vmcnt retires all of buf1
    DS_READS(0, 1, 1);
    stageQ(0, 1, 0, 0, T2); stageQ(0, 1, 1, 0, T2);
    BAR(); LGKM0(); MFMA16(1);
    if (last) { VMW(0); } else { VMW(4); }
    BAR();
    // p4: buf1.kk0.mh0 | stage buf0.kk1 A (tile T2)
    DS_READS(1, 0, 0);
    stageQ(0, 0, 0, 1, T2); stageQ(0, 0, 1, 1, T2);
    BAR(); LGKM0(); MFMA16(0); BAR();
    // p5: buf1.kk0.mh1 | stage buf0.kk1 B
    DS_READS(1, 0, 1);
    stageQ(0, 1, 0, 1, T2); stageQ(0, 1, 1, 1, T2);
    BAR(); LGKM0(); MFMA16(1); BAR();
    // p6: buf1.kk1.mh0 | stage buf1.kk0 A (tile T3)
    DS_READS(1, 1, 0);
    stageQ(1, 0, 0, 0, T3); stageQ(1, 0, 1, 0, T3);
    BAR(); LGKM0(); MFMA16(0); BAR();
    // p7: buf1.kk1.mh1 | stage buf1.kk0 B; vmcnt retires all of next buf0
    DS_READS(1, 1, 1);
    stageQ(1, 1, 0, 0, T3); stageQ(1, 1, 1, 0, T3);
    BAR(); LGKM0(); MFMA16(1);
    if (!last) { VMW(4); }
    BAR();
  }

  // Epilogue. D layout: col = lane&15, row = (lane>>4)*4 + reg  [m89/m91]
  float biasv[4], scv[4];
#pragma unroll
  for (int ni = 0; ni < 4; ni++) {
    const int n = bn0 + wc * 64 + ni * 16 + lr;
    biasv[ni] = bias[n];
    if (MODE == 1 || MODE == 3) scv[ni] = aux[(size_t)b * D_TOK + n];
  }
#pragma unroll
  for (int mi = 0; mi < 8; mi++) {
#pragma unroll
    for (int reg = 0; reg < 4; reg++) {
      const int m = bm0 + wr * 128 + mi * 16 + kg * 4 + reg;
#pragma unroll
      for (int ni = 0; ni < 4; ni++) {
        const int n = bn0 + wc * 64 + ni * 16 + lr;
        float o = acc[mi][ni][reg] + biasv[ni];
        if (MODE == 1 || MODE == 3) o *= scv[ni];
        if (MODE == 2) o += aux[(size_t)m * D_TOK + n];
        if (MODE == 3) {
          Cb[(size_t)m * D_TOK + n] = f32_to_bf16_rne(o);
        } else if (MODE == 4) {
          C[(size_t)m * D_TOK + n] = o;
          Cb[(size_t)m * D_TOK + n] = f32_to_bf16_rne(o);
        } else {
          C[(size_t)m * D_TOK + n] = o;
        }
      }
    }
  }
}

// ---------------------------------------------------------------------------
// alpha[t,h] = (dot(src[t,:], w[h,:]) + bias[h]) * inv_sqrt_dh ; src is bf16.
// One token per wave; W (16x1024 f32 = 64KB) in LDS; 16B/lane global loads.
// ---------------------------------------------------------------------------
__global__ __launch_bounds__(256) void logits_bf(
    const u16* __restrict__ src, const float* __restrict__ w,
    const float* __restrict__ bias, float* __restrict__ alpha) {
  __shared__ float Wl[NH * D_TOK];  // 64 KB
  for (int i = threadIdx.x; i < NH * D_TOK / 4; i += 256)
    reinterpret_cast<float4*>(Wl)[i] = reinterpret_cast<const float4*>(w)[i];
  __syncthreads();

  const int lane = threadIdx.x & 63;
  const int wid = threadIdx.x >> 6;
  for (int t = blockIdx.x * 4 + wid; t < M_TOT; t += gridDim.x * 4) {
    const u16* row = src + (size_t)t * D_TOK;
    float acc[NH];
#pragma unroll
    for (int h = 0; h < NH; h++) acc[h] = 0.f;
#pragma unroll
    for (int i = 0; i < 2; i++) {  // 2 iters x 8 bf16/lane (16B loads)
      const uint4 xv = reinterpret_cast<const uint4*>(row)[i * 64 + lane];
      float x[8];
      x[0] = bf2f((u16)(xv.x & 0xFFFF)); x[1] = bf2f((u16)(xv.x >> 16));
      x[2] = bf2f((u16)(xv.y & 0xFFFF)); x[3] = bf2f((u16)(xv.y >> 16));
      x[4] = bf2f((u16)(xv.z & 0xFFFF)); x[5] = bf2f((u16)(xv.z >> 16));
      x[6] = bf2f((u16)(xv.w & 0xFFFF)); x[7] = bf2f((u16)(xv.w >> 16));
      const int e0 = i * 512 + lane * 8;
#pragma unroll
      for (int h = 0; h < NH; h++) {
        const float4 w0 = *reinterpret_cast<const float4*>(&Wl[h * D_TOK + e0]);
        const float4 w1 =
            *reinterpret_cast<const float4*>(&Wl[h * D_TOK + e0 + 4]);
        acc[h] += x[0] * w0.x + x[1] * w0.y + x[2] * w0.z + x[3] * w0.w +
                  x[4] * w1.x + x[5] * w1.y + x[6] * w1.z + x[7] * w1.w;
      }
    }
#pragma unroll
    for (int h = 0; h < NH; h++) {
      float v = acc[h];
#pragma unroll
      for (int off = 32; off; off >>= 1) v += __shfl_xor(v, off, 64);
      acc[h] = v;
    }
    if (lane == 0) {
#pragma unroll
      for (int h = 0; h < NH; h++)
        alpha[(size_t)t * NH + h] = (acc[h] + bias[h]) * INV_SQRT_DH;
    }
  }
}

// ---------------------------------------------------------------------------
// Per-(b,h): max over tokens + 1/sum(exp). One block per (b,h), 256 thr.
// ---------------------------------------------------------------------------
__global__ __launch_bounds__(256) void softmax_prep(
    const float* __restrict__ al, float* __restrict__ smx,
    float* __restrict__ sinv) {
  __shared__ float red[4];
  const int b = blockIdx.x >> 4, h = blockIdx.x & 15;
  const int tid = threadIdx.x, lane = tid & 63, wid = tid >> 6;
  const float* col = al + (size_t)b * SEQ * NH + h;

  float mx = -INFINITY;
  for (int t = tid; t < SEQ; t += 256) mx = fmaxf(mx, col[(size_t)t * NH]);
#pragma unroll
  for (int off = 32; off; off >>= 1) mx = fmaxf(mx, __shfl_xor(mx, off, 64));
  if (lane == 0) red[wid] = mx;
  __syncthreads();
  mx = fmaxf(fmaxf(red[0], red[1]), fmaxf(red[2], red[3]));
  __syncthreads();

  float s = 0.f;
  for (int t = tid; t < SEQ; t += 256) s += __expf(col[(size_t)t * NH] - mx);
#pragma unroll
  for (int off = 32; off; off >>= 1) s += __shfl_xor(s, off, 64);
  if (lane == 0) red[wid] = s;
  __syncthreads();
  if (tid == 0) {
    const float tot = red[0] + red[1] + red[2] + red[3];
    smx[blockIdx.x] = mx;
    sinv[blockIdx.x] = 1.0f / tot;
  }
}

// ---------------------------------------------------------------------------
// g[b,d] += sum_{t in chunk} exp(al[b,t,h(d)]-mx)*inv * src_bf16[b,t,d]
// Grid: BATCH*(SEQ/64) blocks, 256 thr; thread owns 4 consecutive d.
// ---------------------------------------------------------------------------
__global__ __launch_bounds__(256) void pool_accum_bf(
    const float* __restrict__ al, const u16* __restrict__ src,
    const float* __restrict__ smx, const float* __restrict__ sinv,
    float* __restrict__ g) {
  constexpr int TCH = 64;
  const int b = blockIdx.x / (SEQ / TCH);
  const int t0 = (blockIdx.x % (SEQ / TCH)) * TCH;
  const int d0 = threadIdx.x * 4;
  const int h = d0 >> 6;
  const float mx = smx[b * NH + h];
  const float inv = sinv[b * NH + h];

  float4 acc = make_float4(0.f, 0.f, 0.f, 0.f);
  const float* ap = al + ((size_t)b * SEQ + t0) * NH + h;
  const u16* sp = src + ((size_t)b * SEQ + t0) * D_TOK + d0;
#pragma unroll 2
  for (int t = 0; t < TCH; t++) {
    const float wgt = __expf(ap[(size_t)t * NH] - mx) * inv;
    const ushort4 v = *reinterpret_cast<const ushort4*>(sp + (size_t)t * D_TOK);
    acc.x += wgt * bf2f(v.x);
    acc.y += wgt * bf2f(v.y);
    acc.z += wgt * bf2f(v.z);
    acc.w += wgt * bf2f(v.w);
  }
  float* gp = g + (size_t)b * D_TOK + d0;
  atomicAdd(gp + 0, acc.x);
  atomicAdd(gp + 1, acc.y);
  atomicAdd(gp + 2, acc.z);
  atomicAdd(gp + 3, acc.w);
}

// ---------------------------------------------------------------------------
extern "C" void kernel_launch(void* const* d_in, const int* in_sizes, int n_in,
                              void* d_out, int out_size, void* d_ws,
                              size_t ws_size, hipStream_t stream) {
  const float* x_q   = (const float*)d_in[0];
  const float* x_kv  = (const float*)d_in[1];
  const float* q_w   = (const float*)d_in[2];
  const float* k_w   = (const float*)d_in[3];
  const float* v_w   = (const float*)d_in[4];
  const float* wq_w  = (const float*)d_in[5];
  const float* wk_w  = (const float*)d_in[6];
  const float* out_w = (const float*)d_in[7];
  const float* q_b   = (const float*)d_in[8];
  const float* k_b   = (const float*)d_in[9];
  const float* v_b   = (const float*)d_in[10];
  const float* wq_b  = (const float*)d_in[11];
  const float* wk_b  = (const float*)d_in[12];
  const float* out_b = (const float*)d_in[13];
  float* out = (float*)d_out;

  char* ws = (char*)d_ws;
  const size_t SZ_F32 = (size_t)M_TOT * D_TOK * sizeof(float);  // 128 MiB
  const size_t SZ_BF  = (size_t)M_TOT * D_TOK * sizeof(u16);    // 64 MiB
  const size_t SZ_WBF = (size_t)D_TOK * D_TOK * sizeof(u16);    // 2 MiB
  size_t off = 0;
  float* q      = (float*)(ws + off); off += SZ_F32;   // q f32 (residual)
  char*  pbase  = ws + off;           off += SZ_F32;   // 128 MiB scratch:
  u16*   p_bf   = (u16*)pbase;                          //  first 64 MiB
  u16*   q_bf   = (u16*)(pbase + SZ_BF);                //  second 64 MiB
  u16*   xq_bf  = (u16*)(ws + off);   off += SZ_BF;    // reused as u_bf
  u16*   xkv_bf = (u16*)(ws + off);   off += SZ_BF;
  u16*   qw_bf  = (u16*)(ws + off);   off += SZ_WBF;
  u16*   kw_bf  = (u16*)(ws + off);   off += SZ_WBF;
  u16*   vw_bf  = (u16*)(ws + off);   off += SZ_WBF;
  u16*   ow_bf  = (u16*)(ws + off);   off += SZ_WBF;
  float* al     = (float*)(ws + off); off += (size_t)M_TOT * NH * sizeof(float);
  float* qg     = (float*)(ws + off); off += (size_t)BATCH * D_TOK * sizeof(float);
  float* kglob  = (float*)(ws + off); off += (size_t)BATCH * D_TOK * sizeof(float);
  float* smx0   = (float*)(ws + off); off += BATCH * NH * sizeof(float);
  float* sinv0  = (float*)(ws + off); off += BATCH * NH * sizeof(float);
  float* smx1   = (float*)(ws + off); off += BATCH * NH * sizeof(float);
  float* sinv1  = (float*)(ws + off); off += BATCH * NH * sizeof(float);
  u16* u_bf = xq_bf;  // x_q_bf dead after GEMM0; u written by GEMM2

  const int NX4 = M_TOT * D_TOK / 4;
  const int NW4 = D_TOK * D_TOK / 4;

  hipMemsetAsync(qg, 0, BATCH * D_TOK * sizeof(float), stream);
  hipMemsetAsync(kglob, 0, BATCH * D_TOK * sizeof(float), stream);

  cvt_f32_bf16<<<2048, 256, 0, stream>>>(x_q,   xq_bf,  NX4);
  cvt_f32_bf16<<<2048, 256, 0, stream>>>(x_kv,  xkv_bf, NX4);
  cvt_f32_bf16<<<512,  256, 0, stream>>>(q_w,   qw_bf,  NW4);
  cvt_f32_bf16<<<512,  256, 0, stream>>>(k_w,   kw_bf,  NW4);
  cvt_f32_bf16<<<512,  256, 0, stream>>>(v_w,   vw_bf,  NW4);
  cvt_f32_bf16<<<512,  256, 0, stream>>>(out_w, ow_bf,  NW4);

  const dim3 gg(512), gb(512);  // 128 M-panels x 4 N-panels
  const dim3 pg(BATCH * (SEQ / 64)), pb(256);

  // q = x_q @ q_w^T + q_b   (f32 + bf16 dual write)
  gemm_bf16<4><<<gg, gb, 0, stream>>>(xq_bf, qw_bf, q_b, q, q_bf, nullptr);
  // alpha logits -> softmax prep -> q_global pool (bf16 reads)
  logits_bf<<<512, 256, 0, stream>>>(q_bf, wq_w, wq_b, al);
  softmax_prep<<<BATCH * NH, 256, 0, stream>>>(al, smx0, sinv0);
  pool_accum_bf<<<pg, pb, 0, stream>>>(al, q_bf, smx0, sinv0, qg);
  // p = (x_kv @ k_w^T + k_b) * q_global   (bf16 out)
  gemm_bf16<3><<<gg, gb, 0, stream>>>(xkv_bf, kw_bf, k_b, nullptr, p_bf, qg);
  // beta logits -> softmax prep -> k_global pool
  logits_bf<<<512, 256, 0, stream>>>(p_bf, wk_w, wk_b, al);
  softmax_prep<<<BATCH * NH, 256, 0, stream>>>(al, smx1, sinv1);
  pool_accum_bf<<<pg, pb, 0, stream>>>(al, p_bf, smx1, sinv1, kglob);
  // u = (x_kv @ v_w^T + v_b) * k_global  (bf16 out)
  gemm_bf16<3><<<gg, gb, 0, stream>>>(xkv_bf, vw_bf, v_b, nullptr, u_bf, kglob);
  // out = q + (u @ out_w^T + out_b)
  gemm_bf16<2><<<gg, gb, 0, stream>>>(u_bf, ow_bf, out_b, out, nullptr, q);
}

// Round 6
// 752.031 us; speedup vs baseline: 1.9814x; 1.0218x over previous
//
#include <hip/hip_runtime.h>
#include <cstdint>
#include <cstddef>

#define D_TOK 1024
#define NH 16
#define DH 64
#define BATCH 8
#define SEQ 4096
#define M_TOT (BATCH * SEQ)   // 32768

typedef unsigned short u16;
typedef __attribute__((ext_vector_type(8))) __bf16 bf16x8;
typedef __attribute__((ext_vector_type(4))) float f32x4;

constexpr float INV_SQRT_DH = 0.125f;  // 1/sqrt(64)

__device__ __forceinline__ u16 f32_to_bf16_rne(float f) {
  union { float f; uint32_t u; } c; c.f = f;
  uint32_t r = (c.u + 0x7FFFu + ((c.u >> 16) & 1u)) >> 16;
  return (u16)r;
}
__device__ __forceinline__ float bf2f(u16 u) {
  union { uint32_t i; float f; } c;
  c.i = (uint32_t)u << 16;
  return c.f;
}

#define BAR() __builtin_amdgcn_s_barrier()
#define LGKM0()                                              \
  do {                                                       \
    asm volatile("s_waitcnt lgkmcnt(0)" ::: "memory");       \
    __builtin_amdgcn_sched_barrier(0);                       \
  } while (0)
#define VMW(N)                                               \
  do {                                                       \
    asm volatile("s_waitcnt vmcnt(" #N ")" ::: "memory");    \
    __builtin_amdgcn_sched_barrier(0);                       \
  } while (0)

// ---------------------------------------------------------------------------
// bf16 MFMA GEMM, 256x256 tile, 512 thr (8 waves 2Mx4N).
// Ring-of-4 LDS regions (each 32 k-cols = 32KB), lookahead 3 regions:
// loads retire 6 phases (~1800 cyc) after issue -> HBM latency covered.
// Per region (2 phases): {dsA mh0 + dsB + stage A(r+3); BAR; LGKM0; MFMA16;
// BAR} {dsA mh1 + stage B(r+3); BAR; LGKM0; MFMA16; VMW(8); BAR}.
// Ledger: end of region r leaves regions r+2,r+3 in flight (8 loads/wave);
// tail VMW(4)@r=29, VMW(0)@r=30. Every VMW precedes a barrier.
// LDS chunked layout [kchunk][row][8]: measured 0 bank conflicts, linear in
// global_load_lds write order (wave-uniform base + lane*16B).
// MODE 0 (Q):  Cb0[m,n] = bf16(acc + bias0[n])
// MODE 1 (KV): n<1024 -> Cb0 (k_w path), else Cb1 (v_w path); raw + bias
// MODE 2 (OUT): C[m,n] = acc + bias0[n] + bf2f(Rq[m,n]); W = W0 + b*1M
// ---------------------------------------------------------------------------
template <int MODE, int NN>   // NN = N-panels (N/256)
__global__ __launch_bounds__(512, 2) void gemm_bf16(
    const u16* __restrict__ A, const u16* __restrict__ W0,
    const u16* __restrict__ W1, const float* __restrict__ bias0,
    const float* __restrict__ bias1, float* __restrict__ C,
    u16* __restrict__ Cb0, u16* __restrict__ Cb1,
    const u16* __restrict__ Rq) {
  __shared__ u16 Sh[4][2][2][512 * 8];  // 4 slots x {A,B} x 2 halves x 8KB

  const int tid = threadIdx.x;
  const int lane = tid & 63;
  const int wid = tid >> 6;        // 8 waves
  const int wr = wid >> 2;         // 0..1 : 128-row half of A
  const int wc = wid & 3;          // 0..3 : 64-col quarter of B
  const int wch = wc >> 1;         // B half index
  const int wcl = wc & 1;
  const int lr = lane & 15;
  const int kg = lane >> 4;        // 0..3

  // XCD-chunked bijective swizzle (grid % 8 == 0); n-fastest decode.
  const int wg = blockIdx.x;
  const int cpx = gridDim.x >> 3;
  const int swz = (wg & 7) * cpx + (wg >> 3);
  const int bm0 = (swz / NN) * 256;
  const int bn0 = (swz % NN) * 256;
  const int b = bm0 >> 12;         // batch index (SEQ=4096)

  // Resolve B-matrix pointer / effective n-base per mode (wave-uniform).
  const u16* Bp;
  const float* biasSel;
  int bneff;
  if (MODE == 1) {
    if (bn0 >= D_TOK) { Bp = W1; biasSel = bias1; bneff = bn0 - D_TOK; }
    else              { Bp = W0; biasSel = bias0; bneff = bn0; }
  } else if (MODE == 2) {
    Bp = W0 + (size_t)b * D_TOK * D_TOK; biasSel = bias0; bneff = bn0;
  } else {
    Bp = W0; biasSel = bias0; bneff = bn0;
  }

  f32x4 acc[8][4];
#pragma unroll
  for (int i = 0; i < 8; i++)
#pragma unroll
    for (int j = 0; j < 4; j++) acc[i][j] = (f32x4)0.f;

  // Stage 128 rows x 32 k of matrix mat (0=A,1=B), region reg, into slot.
  auto stageQ = [&](int slot, int mat, int half, int reg) {
    if (reg > 31) return;
    const int kcl = tid >> 7;      // 0..3: k-chunk (8 bf16) within region
    const int r = tid & 127;
    const u16* gp = (mat == 0 ? A + (size_t)(bm0 + half * 128 + r) * D_TOK
                              : Bp + (size_t)(bneff + half * 128 + r) * D_TOK) +
                    reg * 32 + kcl * 8;
    u16* ld = &Sh[slot][mat][half][(size_t)wid * 64 * 8];  // +lane*16B by HW
    __builtin_amdgcn_global_load_lds(
        (const __attribute__((address_space(1))) void*)gp,
        (__attribute__((address_space(3))) void*)ld, 16, 0, 0);
  };

  // Prologue: regions 0,1,2 in flight (12 loads/wave).
#pragma unroll
  for (int rr = 0; rr < 3; ++rr) {
    stageQ(rr, 0, 0, rr); stageQ(rr, 0, 1, rr);
    stageQ(rr, 1, 0, rr); stageQ(rr, 1, 1, rr);
  }
  VMW(8);  // region 0 landed (all waves, pre-barrier)
  BAR();

  for (int r = 0; r < 32; ++r) {
    const int slot = r & 3, nst = (r + 3) & 3;
    bf16x8 af[4], bv[4];
    // ---- phase mh0: A rows [0,64), B (held for both phases) ----
#pragma unroll
    for (int j = 0; j < 4; ++j)
      af[j] = *reinterpret_cast<const bf16x8*>(
          &Sh[slot][0][wr][(kg * 128 + j * 16 + lr) * 8]);
#pragma unroll
    for (int n = 0; n < 4; ++n)
      bv[n] = *reinterpret_cast<const bf16x8*>(
          &Sh[slot][1][wch][(kg * 128 + wcl * 64 + n * 16 + lr) * 8]);
    stageQ(nst, 0, 0, r + 3); stageQ(nst, 0, 1, r + 3);
    BAR(); LGKM0();
    __builtin_amdgcn_s_setprio(1);
#pragma unroll
    for (int j = 0; j < 4; ++j)
#pragma unroll
      for (int n = 0; n < 4; ++n)
        acc[j][n] = __builtin_amdgcn_mfma_f32_16x16x32_bf16(
            af[j], bv[n], acc[j][n], 0, 0, 0);
    __builtin_amdgcn_s_setprio(0);
    BAR();
    // ---- phase mh1: A rows [64,128) ----
#pragma unroll
    for (int j = 0; j < 4; ++j)
      af[j] = *reinterpret_cast<const bf16x8*>(
          &Sh[slot][0][wr][(kg * 128 + 64 + j * 16 + lr) * 8]);
    stageQ(nst, 1, 0, r + 3); stageQ(nst, 1, 1, r + 3);
    BAR(); LGKM0();
    __builtin_amdgcn_s_setprio(1);
#pragma unroll
    for (int j = 0; j < 4; ++j)
#pragma unroll
      for (int n = 0; n < 4; ++n)
        acc[4 + j][n] = __builtin_amdgcn_mfma_f32_16x16x32_bf16(
            af[j], bv[n], acc[4 + j][n], 0, 0, 0);
    __builtin_amdgcn_s_setprio(0);
    if (r < 29) { VMW(8); }        // region r+1 landed; r+2,r+3 flying
    else if (r == 29) { VMW(4); }
    else if (r == 30) { VMW(0); }
    BAR();
  }

  // Epilogue. D layout: col = lane&15, row = (lane>>4)*4 + reg  [m89/m91]
  float biasv[4];
#pragma unroll
  for (int ni = 0; ni < 4; ni++)
    biasv[ni] = biasSel[bneff + wc * 64 + ni * 16 + lr];
#pragma unroll
  for (int mi = 0; mi < 8; mi++) {
#pragma unroll
    for (int reg = 0; reg < 4; reg++) {
      const int m = bm0 + wr * 128 + mi * 16 + kg * 4 + reg;
#pragma unroll
      for (int ni = 0; ni < 4; ni++) {
        const int n = bneff + wc * 64 + ni * 16 + lr;
        float o = acc[mi][ni][reg] + biasv[ni];
        if (MODE == 0) {
          Cb0[(size_t)m * D_TOK + n] = f32_to_bf16_rne(o);
        } else if (MODE == 1) {
          u16* dst = (bn0 >= D_TOK) ? Cb1 : Cb0;
          dst[(size_t)m * D_TOK + n] = f32_to_bf16_rne(o);
        } else {
          C[(size_t)m * D_TOK + n] = o + bf2f(Rq[(size_t)m * D_TOK + n]);
        }
      }
    }
  }
}

// ---------------------------------------------------------------------------
// fp32 -> bf16: x_q and x_kv in one launch (two 8M-float4 ranges).
// ---------------------------------------------------------------------------
__global__ __launch_bounds__(256) void cvt_x2(
    const float* __restrict__ a, const float* __restrict__ bsrc,
    u16* __restrict__ oa, u16* __restrict__ ob) {
  const int half = M_TOT * D_TOK / 4;  // 8M float4
  int i = blockIdx.x * 256 + threadIdx.x;
  const int stride = gridDim.x * 256;
  for (; i < 2 * half; i += stride) {
    const float* src = (i < half) ? a : bsrc;
    u16* dst = (i < half) ? oa : ob;
    const int j = (i < half) ? i : i - half;
    const float4 v = reinterpret_cast<const float4*>(src)[j];
    ushort4 o;
    o.x = f32_to_bf16_rne(v.x);
    o.y = f32_to_bf16_rne(v.y);
    o.z = f32_to_bf16_rne(v.z);
    o.w = f32_to_bf16_rne(v.w);
    reinterpret_cast<ushort4*>(dst)[j] = o;
  }
}

// q_w, k_w, v_w -> bf16, one launch.
__global__ __launch_bounds__(256) void cvt_w3(
    const float* __restrict__ w0, const float* __restrict__ w1,
    const float* __restrict__ w2, u16* __restrict__ o0,
    u16* __restrict__ o1, u16* __restrict__ o2) {
  const int per = D_TOK * D_TOK / 4;  // 262144 float4
  int i = blockIdx.x * 256 + threadIdx.x;
  const int stride = gridDim.x * 256;
  for (; i < 3 * per; i += stride) {
    const int sel = i / per, j = i - sel * per;
    const float* src = sel == 0 ? w0 : (sel == 1 ? w1 : w2);
    u16* dst = sel == 0 ? o0 : (sel == 1 ? o1 : o2);
    const float4 v = reinterpret_cast<const float4*>(src)[j];
    ushort4 o;
    o.x = f32_to_bf16_rne(v.x);
    o.y = f32_to_bf16_rne(v.y);
    o.z = f32_to_bf16_rne(v.z);
    o.w = f32_to_bf16_rne(v.w);
    reinterpret_cast<ushort4*>(dst)[j] = o;
  }
}

// ows[b][n][k] = bf16(out_w[n][k] * kg[b][k])   (fold k_global into weights)
__global__ __launch_bounds__(256) void scale_ow_k(
    const float* __restrict__ ow, const float* __restrict__ kg,
    u16* __restrict__ ows) {
  const int per_b = D_TOK * D_TOK / 4;  // 262144 float4 per batch
  int i = blockIdx.x * 256 + threadIdx.x;
  const int stride = gridDim.x * 256;
  for (; i < BATCH * per_b; i += stride) {
    const int b = i / per_b, j = i - b * per_b;
    const int k4 = j & 255;
    const float4 w = reinterpret_cast<const float4*>(ow)[j];
    const float4 s = reinterpret_cast<const float4*>(kg)[b * 256 + k4];
    ushort4 o;
    o.x = f32_to_bf16_rne(w.x * s.x);
    o.y = f32_to_bf16_rne(w.y * s.y);
    o.z = f32_to_bf16_rne(w.z * s.z);
    o.w = f32_to_bf16_rne(w.w * s.w);
    reinterpret_cast<ushort4*>(ows)[i] = o;
  }
}

// ---------------------------------------------------------------------------
// logits[t,h] = (dot(row[t]*scale, w[h]) + bias[h]) * inv_sqrt_dh
// SCALED: row elements multiplied by qg[b, d] on the fly (p = k * q_global).
// One token per wave; W (16x1024 f32 = 64KB) in LDS; 16B/lane row loads.
// ---------------------------------------------------------------------------
template <int SCALED>
__global__ __launch_bounds__(256) void logits_bf(
    const u16* __restrict__ src, const float* __restrict__ w,
    const float* __restrict__ bias, const float* __restrict__ qg,
    float* __restrict__ alpha) {
  __shared__ float Wl[NH * D_TOK];  // 64 KB
  for (int i = threadIdx.x; i < NH * D_TOK / 4; i += 256)
    reinterpret_cast<float4*>(Wl)[i] = reinterpret_cast<const float4*>(w)[i];
  __syncthreads();

  const int lane = threadIdx.x & 63;
  const int wid = threadIdx.x >> 6;
  for (int t = blockIdx.x * 4 + wid; t < M_TOT; t += gridDim.x * 4) {
    const u16* row = src + (size_t)t * D_TOK;
    const float* gq = qg + (size_t)(t >> 12) * D_TOK;
    float acc[NH];
#pragma unroll
    for (int h = 0; h < NH; h++) acc[h] = 0.f;
#pragma unroll
    for (int i = 0; i < 2; i++) {  // 2 iters x 8 bf16/lane (16B loads)
      const uint4 xv = reinterpret_cast<const uint4*>(row)[i * 64 + lane];
      const int e0 = i * 512 + lane * 8;
      float x[8];
      x[0] = bf2f((u16)(xv.x & 0xFFFF)); x[1] = bf2f((u16)(xv.x >> 16));
      x[2] = bf2f((u16)(xv.y & 0xFFFF)); x[3] = bf2f((u16)(xv.y >> 16));
      x[4] = bf2f((u16)(xv.z & 0xFFFF)); x[5] = bf2f((u16)(xv.z >> 16));
      x[6] = bf2f((u16)(xv.w & 0xFFFF)); x[7] = bf2f((u16)(xv.w >> 16));
      if (SCALED) {
        const float4 g0 = *reinterpret_cast<const float4*>(&gq[e0]);
        const float4 g1 = *reinterpret_cast<const float4*>(&gq[e0 + 4]);
        x[0] *= g0.x; x[1] *= g0.y; x[2] *= g0.z; x[3] *= g0.w;
        x[4] *= g1.x; x[5] *= g1.y; x[6] *= g1.z; x[7] *= g1.w;
      }
#pragma unroll
      for (int h = 0; h < NH; h++) {
        const float4 w0 = *reinterpret_cast<const float4*>(&Wl[h * D_TOK + e0]);
        const float4 w1 =
            *reinterpret_cast<const float4*>(&Wl[h * D_TOK + e0 + 4]);
        acc[h] += x[0] * w0.x + x[1] * w0.y + x[2] * w0.z + x[3] * w0.w +
                  x[4] * w1.x + x[5] * w1.y + x[6] * w1.z + x[7] * w1.w;
      }
    }
#pragma unroll
    for (int h = 0; h < NH; h++) {
      float v = acc[h];
#pragma unroll
      for (int off = 32; off; off >>= 1) v += __shfl_xor(v, off, 64);
      acc[h] = v;
    }
    if (lane == 0) {
#pragma unroll
      for (int h = 0; h < NH; h++)
        alpha[(size_t)t * NH + h] = (acc[h] + bias[h]) * INV_SQRT_DH;
    }
  }
}

// ---------------------------------------------------------------------------
// Per-(b,h): max over tokens + 1/sum(exp). One block per (b,h), 256 thr.
// ---------------------------------------------------------------------------
__global__ __launch_bounds__(256) void softmax_prep(
    const float* __restrict__ al, float* __restrict__ smx,
    float* __restrict__ sinv) {
  __shared__ float red[4];
  const int b = blockIdx.x >> 4, h = blockIdx.x & 15;
  const int tid = threadIdx.x, lane = tid & 63, wid = tid >> 6;
  const float* col = al + (size_t)b * SEQ * NH + h;

  float mx = -INFINITY;
  for (int t = tid; t < SEQ; t += 256) mx = fmaxf(mx, col[(size_t)t * NH]);
#pragma unroll
  for (int off = 32; off; off >>= 1) mx = fmaxf(mx, __shfl_xor(mx, off, 64));
  if (lane == 0) red[wid] = mx;
  __syncthreads();
  mx = fmaxf(fmaxf(red[0], red[1]), fmaxf(red[2], red[3]));
  __syncthreads();

  float s = 0.f;
  for (int t = tid; t < SEQ; t += 256) s += __expf(col[(size_t)t * NH] - mx);
#pragma unroll
  for (int off = 32; off; off >>= 1) s += __shfl_xor(s, off, 64);
  if (lane == 0) red[wid] = s;
  __syncthreads();
  if (tid == 0) {
    const float tot = red[0] + red[1] + red[2] + red[3];
    smx[blockIdx.x] = mx;
    sinv[blockIdx.x] = 1.0f / tot;
  }
}

// ---------------------------------------------------------------------------
// g[b,d] += (SCALED ? qg[b,d] : 1) * sum_{t in chunk} softmaxw[t]*src[b,t,d]
// (qg factors out of the token sum -> applied to the partial before atomic)
// ---------------------------------------------------------------------------
template <int SCALED>
__global__ __launch_bounds__(256) void pool_accum_bf(
    const float* __restrict__ al, const u16* __restrict__ src,
    const float* __restrict__ smx, const float* __restrict__ sinv,
    const float* __restrict__ qg, float* __restrict__ g) {
  constexpr int TCH = 64;
  const int b = blockIdx.x / (SEQ / TCH);
  const int t0 = (blockIdx.x % (SEQ / TCH)) * TCH;
  const int d0 = threadIdx.x * 4;
  const int h = d0 >> 6;
  const float mx = smx[b * NH + h];
  const float inv = sinv[b * NH + h];

  float4 acc = make_float4(0.f, 0.f, 0.f, 0.f);
  const float* ap = al + ((size_t)b * SEQ + t0) * NH + h;
  const u16* sp = src + ((size_t)b * SEQ + t0) * D_TOK + d0;
#pragma unroll 2
  for (int t = 0; t < TCH; t++) {
    const float wgt = __expf(ap[(size_t)t * NH] - mx) * inv;
    const ushort4 v = *reinterpret_cast<const ushort4*>(sp + (size_t)t * D_TOK);
    acc.x += wgt * bf2f(v.x);
    acc.y += wgt * bf2f(v.y);
    acc.z += wgt * bf2f(v.z);
    acc.w += wgt * bf2f(v.w);
  }
  if (SCALED) {
    const float4 s = *reinterpret_cast<const float4*>(&qg[b * D_TOK + d0]);
    acc.x *= s.x; acc.y *= s.y; acc.z *= s.z; acc.w *= s.w;
  }
  float* gp = g + (size_t)b * D_TOK + d0;
  atomicAdd(gp + 0, acc.x);
  atomicAdd(gp + 1, acc.y);
  atomicAdd(gp + 2, acc.z);
  atomicAdd(gp + 3, acc.w);
}

// ---------------------------------------------------------------------------
extern "C" void kernel_launch(void* const* d_in, const int* in_sizes, int n_in,
                              void* d_out, int out_size, void* d_ws,
                              size_t ws_size, hipStream_t stream) {
  const float* x_q   = (const float*)d_in[0];
  const float* x_kv  = (const float*)d_in[1];
  const float* q_w   = (const float*)d_in[2];
  const float* k_w   = (const float*)d_in[3];
  const float* v_w   = (const float*)d_in[4];
  const float* wq_w  = (const float*)d_in[5];
  const float* wk_w  = (const float*)d_in[6];
  const float* out_w = (const float*)d_in[7];
  const float* q_b   = (const float*)d_in[8];
  const float* k_b   = (const float*)d_in[9];
  const float* v_b   = (const float*)d_in[10];
  const float* wq_b  = (const float*)d_in[11];
  const float* wk_b  = (const float*)d_in[12];
  const float* out_b = (const float*)d_in[13];
  float* out = (float*)d_out;

  char* ws = (char*)d_ws;
  const size_t SZ_BF  = (size_t)M_TOT * D_TOK * sizeof(u16);    // 64 MiB
  const size_t SZ_WBF = (size_t)D_TOK * D_TOK * sizeof(u16);    // 2 MiB
  size_t off = 0;
  u16* xq_bf  = (u16*)(ws + off); off += SZ_BF;
  u16* xkv_bf = (u16*)(ws + off); off += SZ_BF;
  u16* q_bf   = (u16*)(ws + off); off += SZ_BF;
  u16* kraw   = (u16*)(ws + off); off += SZ_BF;
  u16* vraw   = (u16*)(ws + off); off += SZ_BF;
  u16* qw_bf  = (u16*)(ws + off); off += SZ_WBF;
  u16* kw_bf  = (u16*)(ws + off); off += SZ_WBF;
  u16* vw_bf  = (u16*)(ws + off); off += SZ_WBF;
  u16* ows    = (u16*)(ws + off); off += BATCH * SZ_WBF;        // 16 MiB
  float* al   = (float*)(ws + off); off += (size_t)M_TOT * NH * sizeof(float);
  float* qg   = (float*)(ws + off); off += (size_t)BATCH * D_TOK * sizeof(float);
  float* kglb = (float*)(ws + off); off += (size_t)BATCH * D_TOK * sizeof(float);
  float* smx0 = (float*)(ws + off); off += BATCH * NH * sizeof(float);
  float* sinv0= (float*)(ws + off); off += BATCH * NH * sizeof(float);
  float* smx1 = (float*)(ws + off); off += BATCH * NH * sizeof(float);
  float* sinv1= (float*)(ws + off); off += BATCH * NH * sizeof(float);

  hipMemsetAsync(qg, 0, BATCH * D_TOK * sizeof(float), stream);
  hipMemsetAsync(kglb, 0, BATCH * D_TOK * sizeof(float), stream);

  cvt_x2<<<2048, 256, 0, stream>>>(x_q, x_kv, xq_bf, xkv_bf);
  cvt_w3<<<512, 256, 0, stream>>>(q_w, k_w, v_w, qw_bf, kw_bf, vw_bf);

  const dim3 pg(BATCH * (SEQ / 64)), pb(256);

  // q = bf16(x_q @ q_w^T + q_b)
  gemm_bf16<0, 4><<<512, 512, 0, stream>>>(xq_bf, qw_bf, nullptr, q_b, nullptr,
                                           nullptr, q_bf, nullptr, nullptr);
  // alpha -> softmax -> q_global
  logits_bf<0><<<512, 256, 0, stream>>>(q_bf, wq_w, wq_b, nullptr, al);
  softmax_prep<<<BATCH * NH, 256, 0, stream>>>(al, smx0, sinv0);
  pool_accum_bf<0><<<pg, pb, 0, stream>>>(al, q_bf, smx0, sinv0, nullptr, qg);
  // fused kv: kraw = x_kv @ k_w^T + k_b ; vraw = x_kv @ v_w^T + v_b
  gemm_bf16<1, 8><<<1024, 512, 0, stream>>>(xkv_bf, kw_bf, vw_bf, k_b, v_b,
                                            nullptr, kraw, vraw, nullptr);
  // beta (p = kraw * qg applied on the fly) -> softmax -> k_global
  logits_bf<1><<<512, 256, 0, stream>>>(kraw, wk_w, wk_b, qg, al);
  softmax_prep<<<BATCH * NH, 256, 0, stream>>>(al, smx1, sinv1);
  pool_accum_bf<1><<<pg, pb, 0, stream>>>(al, kraw, smx1, sinv1, qg, kglb);
  // fold k_global into out_w per batch
  scale_ow_k<<<1024, 256, 0, stream>>>(out_w, kglb, ows);
  // out = q + (vraw * kg) @ out_w^T + out_b  ==  vraw @ ows[b]^T + out_b + q
  gemm_bf16<2, 4><<<512, 512, 0, stream>>>(vraw, ows, nullptr, out_b, nullptr,
                                           out, nullptr, nullptr, q_bf);
}

// Round 7
// 741.445 us; speedup vs baseline: 2.0097x; 1.0143x over previous
//
#include <hip/hip_runtime.h>
#include <cstdint>
#include <cstddef>

#define D_TOK 1024
#define NH 16
#define DH 64
#define BATCH 8
#define SEQ 4096
#define M_TOT (BATCH * SEQ)   // 32768

typedef unsigned short u16;
typedef __attribute__((ext_vector_type(8))) __bf16 bf16x8;
typedef __attribute__((ext_vector_type(4))) float f32x4;

constexpr float INV_SQRT_DH = 0.125f;  // 1/sqrt(64)

__device__ __forceinline__ u16 f32_to_bf16_rne(float f) {
  union { float f; uint32_t u; } c; c.f = f;
  uint32_t r = (c.u + 0x7FFFu + ((c.u >> 16) & 1u)) >> 16;
  return (u16)r;
}
__device__ __forceinline__ float bf2f(u16 u) {
  union { uint32_t i; float f; } c;
  c.i = (uint32_t)u << 16;
  return c.f;
}

#define BAR() __builtin_amdgcn_s_barrier()
#define SCHB() __builtin_amdgcn_sched_barrier(0)
#define LGKM(N)                                                  \
  do {                                                           \
    asm volatile("s_waitcnt lgkmcnt(" #N ")" ::: "memory");      \
    SCHB();                                                      \
  } while (0)
#define VMW(N)                                                   \
  do {                                                           \
    asm volatile("s_waitcnt vmcnt(" #N ")" ::: "memory");        \
    SCHB();                                                      \
  } while (0)

// ---------------------------------------------------------------------------
// bf16 MFMA GEMM, 256x256 tile, 512 thr (8 waves 2Mx4N).
// Ring-of-4 LDS slots (32 k-cols each). Two overlap axes:
//  - vmcnt: stages issued 3 regions ahead, retired by counted VMW(8) (8/4/0 tail)
//  - lgkmcnt: ds_reads issued ONE PHASE ahead, retired by counted LGKM(4/8):
//      mh0: [BAR][stage4 r+3][read afm(slot r hi)][LGKM(4)][MFMA lo]
//      mh1: [VMW(8)][read af0+bv(slot r+1)][LGKM(8)][MFMA hi]
//    so the LDS drain runs concurrently with the MFMA cluster.
// One barrier per region: restage of slot (r+3)&3 ≡ (r-1)&3 is safe because
// every wave's reads of that slot retire at its LGKM(8) in region r-1, which
// precedes the BAR all waves pass before region r's stages issue.
// FIFO ledgers (per thread): ds: 8 -> +4 -> LGKM(4) -> +8 -> LGKM(8) -> 8.
// vmem: 8 -> +4(stage) -> VMW(8) -> 8.  Tail: VMW(4)@r29, VMW(0)@r30.
// LDS chunked layout: elem (kc*128+row)*8+e == staging-linear; 0 conflicts.
// MODE 0 (Q):  Cb0 = bf16(acc + bias0)
// MODE 1 (KV): n<1024 -> Cb0 (k path) else Cb1 (v path)
// MODE 2 (OUT): C = acc + bias0 + bf2f(Rq);  W = W0 + b*1M (pre-scaled)
// ---------------------------------------------------------------------------
template <int MODE, int NN>   // NN = N-panels (N/256)
__global__ __launch_bounds__(512, 2) void gemm_bf16(
    const u16* __restrict__ A, const u16* __restrict__ W0,
    const u16* __restrict__ W1, const float* __restrict__ bias0,
    const float* __restrict__ bias1, float* __restrict__ C,
    u16* __restrict__ Cb0, u16* __restrict__ Cb1,
    const u16* __restrict__ Rq) {
  __shared__ u16 Sh[4][2][2][4096];  // 4 slots x {A,B} x 2 halves x 8KB

  const int tid = threadIdx.x;
  const int lane = tid & 63;
  const int wid = tid >> 6;        // 8 waves
  const int wr = wid >> 2;         // 0..1 : 128-row half of A
  const int wc = wid & 3;          // 0..3 : 64-col quarter of B
  const int wch = wc >> 1;         // B half index
  const int wcl = wc & 1;
  const int lr = lane & 15;
  const int kg = lane >> 4;        // 0..3

  // XCD-chunked bijective swizzle (grid % 8 == 0); n-fastest decode.
  const int wg = blockIdx.x;
  const int cpx = gridDim.x >> 3;
  const int swz = (wg & 7) * cpx + (wg >> 3);
  const int bm0 = (swz / NN) * 256;
  const int bn0 = (swz % NN) * 256;
  const int b = bm0 >> 12;         // batch index (SEQ=4096)

  const u16* Bp;
  const float* biasSel;
  int bneff;
  if (MODE == 1) {
    if (bn0 >= D_TOK) { Bp = W1; biasSel = bias1; bneff = bn0 - D_TOK; }
    else              { Bp = W0; biasSel = bias0; bneff = bn0; }
  } else if (MODE == 2) {
    Bp = W0 + (size_t)b * D_TOK * D_TOK; biasSel = bias0; bneff = bn0;
  } else {
    Bp = W0; biasSel = bias0; bneff = bn0;
  }

  f32x4 acc[8][4];
#pragma unroll
  for (int i = 0; i < 8; i++)
#pragma unroll
    for (int j = 0; j < 4; j++) acc[i][j] = (f32x4)0.f;

  // ---- hoisted addressing ----
  const int srow = tid & 127;          // staging row within 128-half
  const int skc = tid >> 7;            // staging k-chunk (8 bf16)
  const u16* gpA0 = A + (size_t)(bm0 + srow) * D_TOK + skc * 8;
  const u16* gpA1 = gpA0 + (size_t)128 * D_TOK;
  const u16* gpB0 = Bp + (size_t)(bneff + srow) * D_TOK + skc * 8;
  const u16* gpB1 = gpB0 + (size_t)128 * D_TOK;
  const int widOff = wid * 512;        // LDS dest elems (wave-uniform)
  const int aOff = (kg * 128 + lr) * 16;             // byte offset, A frag
  const int bOff = (kg * 128 + wcl * 64 + lr) * 16;  // byte offset, B frag

#define GLD(GP, LP)                                               \
  __builtin_amdgcn_global_load_lds(                               \
      (const __attribute__((address_space(1))) void*)(GP),        \
      (__attribute__((address_space(3))) void*)(LP), 16, 0, 0)

#define STAGE4(SL, REG)                                           \
  do {                                                            \
    const int _o = (REG) * 32;                                    \
    GLD(gpA0 + _o, &Sh[SL][0][0][widOff]);                        \
    GLD(gpA1 + _o, &Sh[SL][0][1][widOff]);                        \
    GLD(gpB0 + _o, &Sh[SL][1][0][widOff]);                        \
    GLD(gpB1 + _o, &Sh[SL][1][1][widOff]);                        \
  } while (0)

#define RD_A0(SL, DST)                                            \
  _Pragma("unroll") for (int j = 0; j < 4; ++j)                   \
      DST[j] = *reinterpret_cast<const bf16x8*>(                  \
          (const char*)&Sh[SL][0][wr][0] + aOff + j * 256)

#define RD_A1(SL, DST)                                            \
  _Pragma("unroll") for (int j = 0; j < 4; ++j)                   \
      DST[j] = *reinterpret_cast<const bf16x8*>(                  \
          (const char*)&Sh[SL][0][wr][0] + 1024 + aOff + j * 256)

#define RD_B(SL, DST)                                             \
  _Pragma("unroll") for (int n = 0; n < 4; ++n)                   \
      DST[n] = *reinterpret_cast<const bf16x8*>(                  \
          (const char*)&Sh[SL][1][wch][0] + bOff + n * 256)

#define MFMA_LO(BV)                                               \
  do {                                                            \
    __builtin_amdgcn_s_setprio(1);                                \
    _Pragma("unroll") for (int j = 0; j < 4; ++j)                 \
        _Pragma("unroll") for (int n = 0; n < 4; ++n)             \
            acc[j][n] = __builtin_amdgcn_mfma_f32_16x16x32_bf16(  \
                af0[j], BV[n], acc[j][n], 0, 0, 0);               \
    __builtin_amdgcn_s_setprio(0);                                \
  } while (0)

#define MFMA_HI(BV)                                               \
  do {                                                            \
    __builtin_amdgcn_s_setprio(1);                                \
    _Pragma("unroll") for (int j = 0; j < 4; ++j)                 \
        _Pragma("unroll") for (int n = 0; n < 4; ++n)             \
            acc[4 + j][n] =                                       \
                __builtin_amdgcn_mfma_f32_16x16x32_bf16(          \
                    afm[j], BV[n], acc[4 + j][n], 0, 0, 0);       \
    __builtin_amdgcn_s_setprio(0);                                \
  } while (0)

  bf16x8 af0[4], afm[4], bvE[4], bvO[4];

  // Prologue: stage slots 0,1,2 (regions 0,1,2); retire slot 0; preload reads.
  STAGE4(0, 0);
  STAGE4(1, 1);
  STAGE4(2, 2);
  VMW(8);
  BAR();
  RD_A0(0, af0);
  RD_B(0, bvE);   // 8 ds outstanding -> steady-state invariant

  // Uniform region body: r in [0,28), slot=r&3, bv parity r&1.
#define UREG(SL, BVC, BVN)                                        \
  do {                                                            \
    BAR();                                                        \
    STAGE4((SL + 3) & 3, rr + 3);                                 \
    RD_A1(SL, afm);                                               \
    LGKM(4);                                                      \
    MFMA_LO(BVC);                                                 \
    VMW(8);                                                       \
    RD_A0((SL + 1) & 3, af0);                                     \
    RD_B((SL + 1) & 3, BVN);                                      \
    LGKM(8);                                                      \
    MFMA_HI(BVC);                                                 \
    ++rr;                                                         \
  } while (0)

  int rr = 0;
  for (int o = 0; o < 7; ++o) {
    UREG(0, bvE, bvO);
    UREG(1, bvO, bvE);
    UREG(2, bvE, bvO);
    UREG(3, bvO, bvE);
  }
  // Peeled tail: r=28..31 (stages beyond region 31 gated off).
  // r=28 (slot 0, bvE): last stage (region 31 -> slot 3).
  BAR();
  STAGE4(3, 31);
  RD_A1(0, afm);
  LGKM(4); MFMA_LO(bvE);
  VMW(8);
  RD_A0(1, af0); RD_B(1, bvO);
  LGKM(8); MFMA_HI(bvE);
  // r=29 (slot 1, bvO): no stage; in-flight 8 -> VMW(4) retires slot 2.
  BAR();
  RD_A1(1, afm);
  LGKM(4); MFMA_LO(bvO);
  VMW(4);
  RD_A0(2, af0); RD_B(2, bvE);
  LGKM(8); MFMA_HI(bvO);
  // r=30 (slot 2, bvE): VMW(0) retires slot 3.
  BAR();
  RD_A1(2, afm);
  LGKM(4); MFMA_LO(bvE);
  VMW(0);
  RD_A0(3, af0); RD_B(3, bvO);
  LGKM(8); MFMA_HI(bvE);
  // r=31 (slot 3, bvO): no next reads.
  BAR();
  RD_A1(3, afm);
  LGKM(4); MFMA_LO(bvO);
  LGKM(0); MFMA_HI(bvO);

#undef UREG
#undef MFMA_LO
#undef MFMA_HI
#undef RD_A0
#undef RD_A1
#undef RD_B
#undef STAGE4
#undef GLD

  // Epilogue. D layout: col = lane&15, row = (lane>>4)*4 + reg  [m89/m91]
  float biasv[4];
#pragma unroll
  for (int ni = 0; ni < 4; ni++)
    biasv[ni] = biasSel[bneff + wc * 64 + ni * 16 + lr];
#pragma unroll
  for (int mi = 0; mi < 8; mi++) {
#pragma unroll
    for (int reg = 0; reg < 4; reg++) {
      const int m = bm0 + wr * 128 + mi * 16 + kg * 4 + reg;
#pragma unroll
      for (int ni = 0; ni < 4; ni++) {
        const int n = bneff + wc * 64 + ni * 16 + lr;
        float o = acc[mi][ni][reg] + biasv[ni];
        if (MODE == 0) {
          Cb0[(size_t)m * D_TOK + n] = f32_to_bf16_rne(o);
        } else if (MODE == 1) {
          u16* dst = (bn0 >= D_TOK) ? Cb1 : Cb0;
          dst[(size_t)m * D_TOK + n] = f32_to_bf16_rne(o);
        } else {
          C[(size_t)m * D_TOK + n] = o + bf2f(Rq[(size_t)m * D_TOK + n]);
        }
      }
    }
  }
}

// ---------------------------------------------------------------------------
// fp32 -> bf16: x_q and x_kv in one launch (two 8M-float4 ranges).
// ---------------------------------------------------------------------------
__global__ __launch_bounds__(256) void cvt_x2(
    const float* __restrict__ a, const float* __restrict__ bsrc,
    u16* __restrict__ oa, u16* __restrict__ ob) {
  const int half = M_TOT * D_TOK / 4;  // 8M float4
  int i = blockIdx.x * 256 + threadIdx.x;
  const int stride = gridDim.x * 256;
  for (; i < 2 * half; i += stride) {
    const float* src = (i < half) ? a : bsrc;
    u16* dst = (i < half) ? oa : ob;
    const int j = (i < half) ? i : i - half;
    const float4 v = reinterpret_cast<const float4*>(src)[j];
    ushort4 o;
    o.x = f32_to_bf16_rne(v.x);
    o.y = f32_to_bf16_rne(v.y);
    o.z = f32_to_bf16_rne(v.z);
    o.w = f32_to_bf16_rne(v.w);
    reinterpret_cast<ushort4*>(dst)[j] = o;
  }
}

// q_w, k_w, v_w -> bf16, one launch.
__global__ __launch_bounds__(256) void cvt_w3(
    const float* __restrict__ w0, const float* __restrict__ w1,
    const float* __restrict__ w2, u16* __restrict__ o0,
    u16* __restrict__ o1, u16* __restrict__ o2) {
  const int per = D_TOK * D_TOK / 4;  // 262144 float4
  int i = blockIdx.x * 256 + threadIdx.x;
  const int stride = gridDim.x * 256;
  for (; i < 3 * per; i += stride) {
    const int sel = i / per, j = i - sel * per;
    const float* src = sel == 0 ? w0 : (sel == 1 ? w1 : w2);
    u16* dst = sel == 0 ? o0 : (sel == 1 ? o1 : o2);
    const float4 v = reinterpret_cast<const float4*>(src)[j];
    ushort4 o;
    o.x = f32_to_bf16_rne(v.x);
    o.y = f32_to_bf16_rne(v.y);
    o.z = f32_to_bf16_rne(v.z);
    o.w = f32_to_bf16_rne(v.w);
    reinterpret_cast<ushort4*>(dst)[j] = o;
  }
}

// ows[b][n][k] = bf16(out_w[n][k] * kg[b][k])   (fold k_global into weights)
__global__ __launch_bounds__(256) void scale_ow_k(
    const float* __restrict__ ow, const float* __restrict__ kg,
    u16* __restrict__ ows) {
  const int per_b = D_TOK * D_TOK / 4;  // 262144 float4 per batch
  int i = blockIdx.x * 256 + threadIdx.x;
  const int stride = gridDim.x * 256;
  for (; i < BATCH * per_b; i += stride) {
    const int b = i / per_b, j = i - b * per_b;
    const int k4 = j & 255;
    const float4 w = reinterpret_cast<const float4*>(ow)[j];
    const float4 s = reinterpret_cast<const float4*>(kg)[b * 256 + k4];
    ushort4 o;
    o.x = f32_to_bf16_rne(w.x * s.x);
    o.y = f32_to_bf16_rne(w.y * s.y);
    o.z = f32_to_bf16_rne(w.z * s.z);
    o.w = f32_to_bf16_rne(w.w * s.w);
    reinterpret_cast<ushort4*>(ows)[i] = o;
  }
}

// ---------------------------------------------------------------------------
// logits[t,h] = (dot(row[t]*scale, w[h]) + bias[h]) * inv_sqrt_dh
// SCALED: row elements multiplied by qg[b, d] on the fly (p = k * q_global).
// ---------------------------------------------------------------------------
template <int SCALED>
__global__ __launch_bounds__(256) void logits_bf(
    const u16* __restrict__ src, const float* __restrict__ w,
    const float* __restrict__ bias, const float* __restrict__ qg,
    float* __restrict__ alpha) {
  __shared__ float Wl[NH * D_TOK];  // 64 KB
  for (int i = threadIdx.x; i < NH * D_TOK / 4; i += 256)
    reinterpret_cast<float4*>(Wl)[i] = reinterpret_cast<const float4*>(w)[i];
  __syncthreads();

  const int lane = threadIdx.x & 63;
  const int wid = threadIdx.x >> 6;
  for (int t = blockIdx.x * 4 + wid; t < M_TOT; t += gridDim.x * 4) {
    const u16* row = src + (size_t)t * D_TOK;
    const float* gq = qg + (size_t)(t >> 12) * D_TOK;
    float acc[NH];
#pragma unroll
    for (int h = 0; h < NH; h++) acc[h] = 0.f;
#pragma unroll
    for (int i = 0; i < 2; i++) {  // 2 iters x 8 bf16/lane (16B loads)
      const uint4 xv = reinterpret_cast<const uint4*>(row)[i * 64 + lane];
      const int e0 = i * 512 + lane * 8;
      float x[8];
      x[0] = bf2f((u16)(xv.x & 0xFFFF)); x[1] = bf2f((u16)(xv.x >> 16));
      x[2] = bf2f((u16)(xv.y & 0xFFFF)); x[3] = bf2f((u16)(xv.y >> 16));
      x[4] = bf2f((u16)(xv.z & 0xFFFF)); x[5] = bf2f((u16)(xv.z >> 16));
      x[6] = bf2f((u16)(xv.w & 0xFFFF)); x[7] = bf2f((u16)(xv.w >> 16));
      if (SCALED) {
        const float4 g0 = *reinterpret_cast<const float4*>(&gq[e0]);
        const float4 g1 = *reinterpret_cast<const float4*>(&gq[e0 + 4]);
        x[0] *= g0.x; x[1] *= g0.y; x[2] *= g0.z; x[3] *= g0.w;
        x[4] *= g1.x; x[5] *= g1.y; x[6] *= g1.z; x[7] *= g1.w;
      }
#pragma unroll
      for (int h = 0; h < NH; h++) {
        const float4 w0 = *reinterpret_cast<const float4*>(&Wl[h * D_TOK + e0]);
        const float4 w1 =
            *reinterpret_cast<const float4*>(&Wl[h * D_TOK + e0 + 4]);
        acc[h] += x[0] * w0.x + x[1] * w0.y + x[2] * w0.z + x[3] * w0.w +
                  x[4] * w1.x + x[5] * w1.y + x[6] * w1.z + x[7] * w1.w;
      }
    }
#pragma unroll
    for (int h = 0; h < NH; h++) {
      float v = acc[h];
#pragma unroll
      for (int off = 32; off; off >>= 1) v += __shfl_xor(v, off, 64);
      acc[h] = v;
    }
    if (lane == 0) {
#pragma unroll
      for (int h = 0; h < NH; h++)
        alpha[(size_t)t * NH + h] = (acc[h] + bias[h]) * INV_SQRT_DH;
    }
  }
}

// ---------------------------------------------------------------------------
// Per-(b,h): max over tokens + 1/sum(exp). One block per (b,h), 256 thr.
// ---------------------------------------------------------------------------
__global__ __launch_bounds__(256) void softmax_prep(
    const float* __restrict__ al, float* __restrict__ smx,
    float* __restrict__ sinv) {
  __shared__ float red[4];
  const int b = blockIdx.x >> 4, h = blockIdx.x & 15;
  const int tid = threadIdx.x, lane = tid & 63, wid = tid >> 6;
  const float* col = al + (size_t)b * SEQ * NH + h;

  float mx = -INFINITY;
  for (int t = tid; t < SEQ; t += 256) mx = fmaxf(mx, col[(size_t)t * NH]);
#pragma unroll
  for (int off = 32; off; off >>= 1) mx = fmaxf(mx, __shfl_xor(mx, off, 64));
  if (lane == 0) red[wid] = mx;
  __syncthreads();
  mx = fmaxf(fmaxf(red[0], red[1]), fmaxf(red[2], red[3]));
  __syncthreads();

  float s = 0.f;
  for (int t = tid; t < SEQ; t += 256) s += __expf(col[(size_t)t * NH] - mx);
#pragma unroll
  for (int off = 32; off; off >>= 1) s += __shfl_xor(s, off, 64);
  if (lane == 0) red[wid] = s;
  __syncthreads();
  if (tid == 0) {
    const float tot = red[0] + red[1] + red[2] + red[3];
    smx[blockIdx.x] = mx;
    sinv[blockIdx.x] = 1.0f / tot;
  }
}

// ---------------------------------------------------------------------------
// g[b,d] += (SCALED ? qg[b,d] : 1) * sum_{t in chunk} softmaxw[t]*src[b,t,d]
// ---------------------------------------------------------------------------
template <int SCALED>
__global__ __launch_bounds__(256) void pool_accum_bf(
    const float* __restrict__ al, const u16* __restrict__ src,
    const float* __restrict__ smx, const float* __restrict__ sinv,
    const float* __restrict__ qg, float* __restrict__ g) {
  constexpr int TCH = 64;
  const int b = blockIdx.x / (SEQ / TCH);
  const int t0 = (blockIdx.x % (SEQ / TCH)) * TCH;
  const int d0 = threadIdx.x * 4;
  const int h = d0 >> 6;
  const float mx = smx[b * NH + h];
  const float inv = sinv[b * NH + h];

  float4 acc = make_float4(0.f, 0.f, 0.f, 0.f);
  const float* ap = al + ((size_t)b * SEQ + t0) * NH + h;
  const u16* sp = src + ((size_t)b * SEQ + t0) * D_TOK + d0;
#pragma unroll 2
  for (int t = 0; t < TCH; t++) {
    const float wgt = __expf(ap[(size_t)t * NH] - mx) * inv;
    const ushort4 v = *reinterpret_cast<const ushort4*>(sp + (size_t)t * D_TOK);
    acc.x += wgt * bf2f(v.x);
    acc.y += wgt * bf2f(v.y);
    acc.z += wgt * bf2f(v.z);
    acc.w += wgt * bf2f(v.w);
  }
  if (SCALED) {
    const float4 s = *reinterpret_cast<const float4*>(&qg[b * D_TOK + d0]);
    acc.x *= s.x; acc.y *= s.y; acc.z *= s.z; acc.w *= s.w;
  }
  float* gp = g + (size_t)b * D_TOK + d0;
  atomicAdd(gp + 0, acc.x);
  atomicAdd(gp + 1, acc.y);
  atomicAdd(gp + 2, acc.z);
  atomicAdd(gp + 3, acc.w);
}

// ---------------------------------------------------------------------------
extern "C" void kernel_launch(void* const* d_in, const int* in_sizes, int n_in,
                              void* d_out, int out_size, void* d_ws,
                              size_t ws_size, hipStream_t stream) {
  const float* x_q   = (const float*)d_in[0];
  const float* x_kv  = (const float*)d_in[1];
  const float* q_w   = (const float*)d_in[2];
  const float* k_w   = (const float*)d_in[3];
  const float* v_w   = (const float*)d_in[4];
  const float* wq_w  = (const float*)d_in[5];
  const float* wk_w  = (const float*)d_in[6];
  const float* out_w = (const float*)d_in[7];
  const float* q_b   = (const float*)d_in[8];
  const float* k_b   = (const float*)d_in[9];
  const float* v_b   = (const float*)d_in[10];
  const float* wq_b  = (const float*)d_in[11];
  const float* wk_b  = (const float*)d_in[12];
  const float* out_b = (const float*)d_in[13];
  float* out = (float*)d_out;

  char* ws = (char*)d_ws;
  const size_t SZ_BF  = (size_t)M_TOT * D_TOK * sizeof(u16);    // 64 MiB
  const size_t SZ_WBF = (size_t)D_TOK * D_TOK * sizeof(u16);    // 2 MiB
  size_t off = 0;
  u16* xq_bf  = (u16*)(ws + off); off += SZ_BF;
  u16* xkv_bf = (u16*)(ws + off); off += SZ_BF;
  u16* q_bf   = (u16*)(ws + off); off += SZ_BF;
  u16* kraw   = (u16*)(ws + off); off += SZ_BF;
  u16* vraw   = (u16*)(ws + off); off += SZ_BF;
  u16* qw_bf  = (u16*)(ws + off); off += SZ_WBF;
  u16* kw_bf  = (u16*)(ws + off); off += SZ_WBF;
  u16* vw_bf  = (u16*)(ws + off); off += SZ_WBF;
  u16* ows    = (u16*)(ws + off); off += BATCH * SZ_WBF;        // 16 MiB
  float* al   = (float*)(ws + off); off += (size_t)M_TOT * NH * sizeof(float);
  float* qg   = (float*)(ws + off); off += (size_t)BATCH * D_TOK * sizeof(float);
  float* kglb = (float*)(ws + off); off += (size_t)BATCH * D_TOK * sizeof(float);
  float* smx0 = (float*)(ws + off); off += BATCH * NH * sizeof(float);
  float* sinv0= (float*)(ws + off); off += BATCH * NH * sizeof(float);
  float* smx1 = (float*)(ws + off); off += BATCH * NH * sizeof(float);
  float* sinv1= (float*)(ws + off); off += BATCH * NH * sizeof(float);

  hipMemsetAsync(qg, 0, BATCH * D_TOK * sizeof(float), stream);
  hipMemsetAsync(kglb, 0, BATCH * D_TOK * sizeof(float), stream);

  cvt_x2<<<2048, 256, 0, stream>>>(x_q, x_kv, xq_bf, xkv_bf);
  cvt_w3<<<512, 256, 0, stream>>>(q_w, k_w, v_w, qw_bf, kw_bf, vw_bf);

  const dim3 pg(BATCH * (SEQ / 64)), pb(256);

  // q = bf16(x_q @ q_w^T + q_b)
  gemm_bf16<0, 4><<<512, 512, 0, stream>>>(xq_bf, qw_bf, nullptr, q_b, nullptr,
                                           nullptr, q_bf, nullptr, nullptr);
  // alpha -> softmax -> q_global
  logits_bf<0><<<512, 256, 0, stream>>>(q_bf, wq_w, wq_b, nullptr, al);
  softmax_prep<<<BATCH * NH, 256, 0, stream>>>(al, smx0, sinv0);
  pool_accum_bf<0><<<pg, pb, 0, stream>>>(al, q_bf, smx0, sinv0, nullptr, qg);
  // fused kv: kraw = x_kv @ k_w^T + k_b ; vraw = x_kv @ v_w^T + v_b
  gemm_bf16<1, 8><<<1024, 512, 0, stream>>>(xkv_bf, kw_bf, vw_bf, k_b, v_b,
                                            nullptr, kraw, vraw, nullptr);
  // beta (p = kraw * qg applied on the fly) -> softmax -> k_global
  logits_bf<1><<<512, 256, 0, stream>>>(kraw, wk_w, wk_b, qg, al);
  softmax_prep<<<BATCH * NH, 256, 0, stream>>>(al, smx1, sinv1);
  pool_accum_bf<1><<<pg, pb, 0, stream>>>(al, kraw, smx1, sinv1, qg, kglb);
  // fold k_global into out_w per batch
  scale_ow_k<<<1024, 256, 0, stream>>>(out_w, kglb, ows);
  // out = q + (vraw * kg) @ out_w^T + out_b  ==  vraw @ ows[b]^T + out_b + q
  gemm_bf16<2, 4><<<512, 512, 0, stream>>>(vraw, ows, nullptr, out_b, nullptr,
                                           out, nullptr, nullptr, q_bf);
}